// Round 1
// baseline (3096.422 us; speedup 1.0000x reference)
//
#include <hip/hip_runtime.h>

typedef unsigned short u16;
typedef unsigned int   u32;
typedef float  f4v    __attribute__((ext_vector_type(4)));
typedef short  short8 __attribute__((ext_vector_type(8)));
typedef __bf16 bf16x8 __attribute__((ext_vector_type(8)));

// ws layout (bytes):
//   W14B   @ 0          524288   (w1,w2,w3,w6 bf16)
//   WCATB  @ 524288     524288
//   W6P    @ 1048576    51380224 ([2048][12544] bf16, permuted k'=n*256+c)
//   W7B    @ 52428800   4194304  ([2][1024][1024] bf16)
//   BIAS6  @ 56623104   8192     ([2048] f32)
//   POOL   @ 56631296   104857600  ([204800][256] bf16)  -- XF overlays after K2/K3
//   ATTN   @ 161488896  40140800   ([4096][2450] f32)    -- XC1 overlays after K3
//   Y      @ 201629696  104857600  ([204800][256] bf16)
// total = 306487296 bytes

__device__ __forceinline__ u16 f2bf(float f) {
  union { float f; u32 u; } v; v.f = f;
  return (u16)((v.u + 0x7FFFu + ((v.u >> 16) & 1u)) >> 16);
}

__device__ __forceinline__ int seg_gb(int k) { return (k == 0) ? 0 : (k == 1) ? 4096 : (k == 2) ? 20480 : 57344; }
__device__ __forceinline__ int seg_pc(int k) { return (k == 0) ? 1 : (k == 1) ? 4 : (k == 2) ? 9 : 36; }
__device__ __forceinline__ int seg_s0(int k) { return (k == 0) ? 0 : (k == 1) ? 1 : (k == 2) ? 5 : 14; }

// ---------------- K0: pack / convert / permute weights ----------------
__global__ __launch_bounds__(256) void k_pack(
    const float* __restrict__ w1, const float* __restrict__ w2,
    const float* __restrict__ w3, const float* __restrict__ w6,
    const float* __restrict__ wcat,
    const float* __restrict__ f6c, const float* __restrict__ f6r,
    const float* __restrict__ f7c, const float* __restrict__ f7r,
    const float* __restrict__ b6c, const float* __restrict__ b6r,
    u16* __restrict__ W14B, u16* __restrict__ WCATB, u16* __restrict__ W6P,
    u16* __restrict__ W7B, float* __restrict__ BIAS6)
{
  const u32 total = 28313600u;
  for (u32 t = blockIdx.x * 256u + threadIdx.x; t < total; t += gridDim.x * 256u) {
    if (t < 262144u) {
      u32 a = t >> 16, i = t & 65535u;
      const float* s = (a == 0) ? w1 : (a == 1) ? w2 : (a == 2) ? w3 : w6;
      W14B[t] = f2bf(s[i]);
    } else if (t < 524288u) {
      u32 i = t - 262144u;
      WCATB[i] = f2bf(wcat[i]);
    } else if (t < 26214400u) {
      u32 j = t - 524288u;
      u32 r = j / 12544u, rem = j - r * 12544u;
      u32 n = rem >> 8, c = rem & 255u;  // out index = n*256 + c
      const float* s = (r < 1024u) ? f6c : f6r;
      W6P[j] = f2bf(s[(size_t)(r & 1023u) * 12544u + c * 49u + n]);
    } else if (t < 28311552u) {
      u32 j = t - 26214400u;
      W7B[j] = f2bf((j < 1048576u) ? f7c[j] : f7r[j - 1048576u]);
    } else {
      u32 j = t - 28311552u;
      BIAS6[j] = (j < 1024u) ? b6c[j] : b6r[j - 1024u];
    }
  }
}

// ---------------- K1: per-sample pooled + scores + softmax ----------------
#define XST 260
#define SST 52

__device__ __forceinline__ void pool_geom(int p, int& k, int& pl, int& r0, int& nr, int& c0, int& nc) {
  if (p == 0)      { k = 0; pl = 0;      r0 = 0; nr = 7; c0 = 0; nc = 7; }
  else if (p < 5)  { k = 1; pl = p - 1;  int i = pl >> 1, j = pl & 1; r0 = i * 3; nr = 4; c0 = j * 3; nc = 4; }
  else if (p < 14) { k = 2; pl = p - 5;  int i = pl / 3,  j = pl % 3; r0 = i * 2; nr = 3; c0 = j * 2; nc = 3; }
  else             { k = 3; pl = p - 14; int i = pl / 6,  j = pl % 6; r0 = i;     nr = 2; c0 = j;     nc = 2; }
}

__global__ __launch_bounds__(1024) void k_pool_attn(
    const float* __restrict__ x, u16* __restrict__ POOL, float* __restrict__ ATTN)
{
  __shared__ float XsT[49 * XST];  // [n][c]
  __shared__ float PsT[50 * XST];  // [p][c]
  __shared__ float Ss[49 * SST];   // [n][p]
  const int b = blockIdx.x;
  const int t = threadIdx.x;
  const float* xb = x + (size_t)b * 12544;

  for (int j = t; j < 12544; j += 1024) {
    int c = j / 49, n = j - c * 49;
    XsT[n * XST + c] = xb[j];
  }
  __syncthreads();

  for (int j = t; j < 12800; j += 1024) {
    int p = j >> 8, c = j & 255;
    int k, pl, r0, nr, c0, nc;
    pool_geom(p, k, pl, r0, nr, c0, nc);
    float s = 0.f;
    for (int r = 0; r < nr; ++r)
      for (int q = 0; q < nc; ++q)
        s += XsT[((r0 + r) * 7 + c0 + q) * XST + c];
    s *= (1.0f / (float)(nr * nc));
    PsT[p * XST + c] = s;
    POOL[((size_t)(seg_gb(k) + b * seg_pc(k) + pl)) * 256 + c] = f2bf(s);
  }
  __syncthreads();

  for (int pr = t; pr < 2450; pr += 1024) {
    int n = pr / 50, p = pr - n * 50;
    const f4v* xr = (const f4v*)(XsT + n * XST);
    const f4v* pq = (const f4v*)(PsT + p * XST);
    float s = 0.f;
    #pragma unroll 8
    for (int i = 0; i < 64; ++i) {
      f4v a = xr[i], bb = pq[i];
      s += a[0] * bb[0] + a[1] * bb[1] + a[2] * bb[2] + a[3] * bb[3];
    }
    Ss[n * SST + p] = s;
  }
  __syncthreads();

  if (t < 196) {
    int n = t >> 2, k = t & 3;
    int s0 = seg_s0(k), pc = seg_pc(k);
    float m = -3.0e38f;
    for (int i = 0; i < pc; ++i) m = fmaxf(m, Ss[n * SST + s0 + i]);
    float sum = 0.f;
    for (int i = 0; i < pc; ++i) sum += __expf(Ss[n * SST + s0 + i] - m);
    float inv = 1.0f / sum;
    float* ab = ATTN + (size_t)b * 2450 + n * 50 + s0;
    for (int i = 0; i < pc; ++i) ab[i] = __expf(Ss[n * SST + s0 + i] - m) * inv;
  }
}

// ---------------- K3': per-sample scat = relu(attn@Y), then xf = x + wcat@scat ----------------
#define SCO 1032

__global__ __launch_bounds__(512) void k_scat_conv(
    const u16* __restrict__ Y, const float* __restrict__ ATTN,
    const u16* __restrict__ WCATB, const float* __restrict__ x,
    u16* __restrict__ XF)
{
  __shared__ u16 scatT[64 * SCO];  // [n(pad64)][o 0..1023], bf16
  __shared__ float attnS[2450];
  const int b = blockIdx.x;
  const int t = threadIdx.x;

  for (int i = t; i < 2450; i += 512) attnS[i] = ATTN[(size_t)b * 2450 + i];
  {
    u32* z = (u32*)(scatT + 49 * SCO);
    for (int i = t; i < 7740; i += 512) z[i] = 0u;  // zero rows 49..63
  }
  __syncthreads();

  for (int task = t; task < 3136; task += 512) {  // 49 n * 64 o-chunks
    int n = task % 49, oc = task / 49;
    int k = oc >> 4;
    int c16 = (oc & 15) * 16;
    int pc = seg_pc(k), s0 = seg_s0(k), gb = seg_gb(k);
    const u16* ybase = Y + ((size_t)(gb + b * pc)) * 256 + c16;
    float s[16];
    #pragma unroll
    for (int j = 0; j < 16; ++j) s[j] = 0.f;
    for (int p = 0; p < pc; ++p) {
      float a = attnS[n * 50 + s0 + p];
      const u16* yp = ybase + (size_t)p * 256;
      u32 yw[8];
      *(int4*)(&yw[0]) = *(const int4*)(yp);
      *(int4*)(&yw[4]) = *(const int4*)(yp + 8);
      #pragma unroll
      for (int j = 0; j < 8; ++j) {
        union { u32 u; float f; } lo, hi;
        lo.u = (yw[j] & 0xFFFFu) << 16;
        hi.u = yw[j] & 0xFFFF0000u;
        s[2 * j]     += a * lo.f;
        s[2 * j + 1] += a * hi.f;
      }
    }
    u16 ov[16];
    #pragma unroll
    for (int j = 0; j < 16; ++j) ov[j] = f2bf(fmaxf(s[j], 0.f));
    *(int4*)(&scatT[n * SCO + oc * 16])     = *(const int4*)(&ov[0]);
    *(int4*)(&scatT[n * SCO + oc * 16 + 8]) = *(const int4*)(&ov[8]);
  }
  __syncthreads();

  // MFMA: XF[n][c] = x[b][c][n] + sum_o scatT[n][o] * wcat[c][o]
  const int l = t & 63, w = t >> 6;
  const int lr = l & 15, lg = l >> 4;
  f4v acc[4][2] = {};
  for (int ks = 0; ks < 32; ++ks) {
    int o0 = ks * 32;
    short8 af[4];
    short8 bfv[2];
    #pragma unroll
    for (int mi = 0; mi < 4; ++mi) {
      int n = mi * 16 + lr;
      af[mi] = *(const short8*)(&scatT[n * SCO + o0 + lg * 8]);
    }
    #pragma unroll
    for (int cc = 0; cc < 2; ++cc) {
      int c = (w * 2 + cc) * 16 + lr;
      bfv[cc] = *(const short8*)(WCATB + (size_t)c * 1024 + o0 + lg * 8);
    }
    #pragma unroll
    for (int mi = 0; mi < 4; ++mi)
      #pragma unroll
      for (int cc = 0; cc < 2; ++cc)
        acc[mi][cc] = __builtin_amdgcn_mfma_f32_16x16x32_bf16(
            __builtin_bit_cast(bf16x8, af[mi]),
            __builtin_bit_cast(bf16x8, bfv[cc]),
            acc[mi][cc], 0, 0, 0);
  }
  #pragma unroll
  for (int mi = 0; mi < 4; ++mi) {
    #pragma unroll
    for (int cc = 0; cc < 2; ++cc) {
      int c = (w * 2 + cc) * 16 + lr;
      #pragma unroll
      for (int j = 0; j < 4; ++j) {
        int n = mi * 16 + lg * 4 + j;
        if (n < 49) {
          float v = acc[mi][cc][j] + x[(size_t)b * 12544 + (size_t)c * 49 + n];
          XF[((size_t)b * 49 + n) * 256 + c] = f2bf(v);
        }
      }
    }
  }
}

// ---------------- generic 128x128 bf16 MFMA GEMM: C = A[M,K] * W[N,K]^T ----------------
template<bool BIAS, bool RELU, bool OBF16>
__global__ __launch_bounds__(256) void gemm_k(
    const u16* __restrict__ A, int lda,
    const u16* __restrict__ W, int ldb,
    void* __restrict__ Cout, int ldc,
    int M, int N, int K, const float* __restrict__ bias, int ntiles)
{
  __shared__ int4 lds4[2048];  // A tile 16KB | B tile 16KB, XOR-swizzled
  char* ldsA = (char*)lds4;
  char* ldsB = (char*)(lds4 + 1024);
  const int tid = threadIdx.x;
  const int bx = blockIdx.x;
  const int mt = bx / ntiles, nt = bx - mt * ntiles;
  const int m0 = mt * 128, n0 = nt * 128;
  const int l = tid & 63, w = tid >> 6;
  const int wr = (w >> 1) * 64, wc = (w & 1) * 64;
  const int lr = l & 15, lg = l >> 4;

  int4 ar[4], br[4];
  auto stage = [&](int kt) {
    #pragma unroll
    for (int it = 0; it < 4; ++it) {
      int q = it * 256 + tid;
      int r = q >> 3, g = q & 7;
      ar[it] = *(const int4*)(A + (size_t)(m0 + r) * lda + kt + g * 8);
      br[it] = *(const int4*)(W + (size_t)(n0 + r) * ldb + kt + g * 8);
    }
  };
  stage(0);

  f4v acc[4][4] = {};
  for (int kt = 0; kt < K; kt += 64) {
    __syncthreads();
    #pragma unroll
    for (int it = 0; it < 4; ++it) {
      int q = it * 256 + tid;
      int r = q >> 3, g = q & 7;
      int off = r * 128 + ((g * 16) ^ ((r & 7) << 4));
      *(int4*)(ldsA + off) = ar[it];
      *(int4*)(ldsB + off) = br[it];
    }
    __syncthreads();
    if (kt + 64 < K) stage(kt + 64);
    #pragma unroll
    for (int kk = 0; kk < 2; ++kk) {
      short8 af[4], bfv[4];
      #pragma unroll
      for (int mi = 0; mi < 4; ++mi) {
        int r = wr + mi * 16 + lr;
        af[mi] = *(const short8*)(ldsA + r * 128 + ((kk * 64 + lg * 16) ^ ((r & 7) << 4)));
      }
      #pragma unroll
      for (int ni = 0; ni < 4; ++ni) {
        int r = wc + ni * 16 + lr;
        bfv[ni] = *(const short8*)(ldsB + r * 128 + ((kk * 64 + lg * 16) ^ ((r & 7) << 4)));
      }
      #pragma unroll
      for (int mi = 0; mi < 4; ++mi)
        #pragma unroll
        for (int ni = 0; ni < 4; ++ni)
          acc[mi][ni] = __builtin_amdgcn_mfma_f32_16x16x32_bf16(
              __builtin_bit_cast(bf16x8, af[mi]),
              __builtin_bit_cast(bf16x8, bfv[ni]),
              acc[mi][ni], 0, 0, 0);
    }
  }

  #pragma unroll
  for (int ni = 0; ni < 4; ++ni) {
    int gc = n0 + wc + ni * 16 + lr;
    float bv = 0.f;
    if (BIAS) bv = bias[gc];
    #pragma unroll
    for (int mi = 0; mi < 4; ++mi) {
      #pragma unroll
      for (int j = 0; j < 4; ++j) {
        int gr = m0 + wr + mi * 16 + lg * 4 + j;
        float v = acc[mi][ni][j] + bv;
        if (RELU) v = fmaxf(v, 0.f);
        if (OBF16) ((u16*)Cout)[(size_t)gr * ldc + gc] = f2bf(v);
        else       ((float*)Cout)[(size_t)gr * ldc + gc] = v;
      }
    }
  }
}

extern "C" void kernel_launch(void* const* d_in, const int* in_sizes, int n_in,
                              void* d_out, int out_size, void* d_ws, size_t ws_size,
                              hipStream_t stream)
{
  (void)in_sizes; (void)n_in; (void)out_size; (void)ws_size;
  const float* x    = (const float*)d_in[0];
  const float* w1   = (const float*)d_in[1];
  const float* w2   = (const float*)d_in[2];
  const float* w3   = (const float*)d_in[3];
  const float* w6   = (const float*)d_in[4];
  const float* wcat = (const float*)d_in[5];
  const float* f6cw = (const float*)d_in[6];
  const float* f6cb = (const float*)d_in[7];
  const float* f7cw = (const float*)d_in[8];
  const float* f7cb = (const float*)d_in[9];
  const float* f6rw = (const float*)d_in[10];
  const float* f6rb = (const float*)d_in[11];
  const float* f7rw = (const float*)d_in[12];
  const float* f7rb = (const float*)d_in[13];

  char* ws = (char*)d_ws;
  u16*   W14B  = (u16*)(ws);
  u16*   WCATB = (u16*)(ws + 524288);
  u16*   W6P   = (u16*)(ws + 1048576);
  u16*   W7B   = (u16*)(ws + 52428800);
  float* BIAS6 = (float*)(ws + 56623104);
  u16*   POOL  = (u16*)(ws + 56631296);
  u16*   XF    = POOL;                      // overlay: POOL dead after K2
  float* ATTN  = (float*)(ws + 161488896);
  u16*   XC1   = (u16*)(ws + 161488896);    // overlay: ATTN dead after K3'
  u16*   Y     = (u16*)(ws + 201629696);

  k_pack<<<dim3(2048), dim3(256), 0, stream>>>(w1, w2, w3, w6, wcat, f6cw, f6rw,
                                               f7cw, f7rw, f6cb, f6rb,
                                               W14B, WCATB, W6P, W7B, BIAS6);
  k_pool_attn<<<dim3(4096), dim3(1024), 0, stream>>>(x, POOL, ATTN);

  for (int k = 0; k < 4; ++k) {
    int gb = (k == 0) ? 0 : (k == 1) ? 4096 : (k == 2) ? 20480 : 57344;
    int pc = (k == 0) ? 1 : (k == 1) ? 4 : (k == 2) ? 9 : 36;
    int M = 4096 * pc;
    gemm_k<false, false, true><<<dim3((M / 128) * 2), dim3(256), 0, stream>>>(
        POOL + (size_t)gb * 256, 256, W14B + k * 65536, 256,
        (void*)(Y + (size_t)gb * 256), 256, M, 256, 256, nullptr, 2);
  }

  k_scat_conv<<<dim3(4096), dim3(512), 0, stream>>>(Y, ATTN, WCATB, x, XF);

  gemm_k<true, true, true><<<dim3(32 * 16), dim3(256), 0, stream>>>(
      XF, 12544, W6P, 12544, (void*)XC1, 2048, 4096, 2048, 12544, BIAS6, 16);

  float* out = (float*)d_out;
  gemm_k<true, false, false><<<dim3(32 * 8), dim3(256), 0, stream>>>(
      XC1, 2048, W7B, 1024, (void*)out, 1024, 4096, 1024, 1024, f7cb, 8);
  gemm_k<true, true, false><<<dim3(32 * 8), dim3(256), 0, stream>>>(
      XC1 + 1024, 2048, W7B + 1048576, 1024,
      (void*)(out + (size_t)4096 * 1024), 1024, 4096, 1024, 1024, f7rb, 8);
}

// Round 3
// 2089.048 us; speedup vs baseline: 1.4822x; 1.4822x over previous
//
#include <hip/hip_runtime.h>

typedef unsigned short u16;
typedef unsigned int   u32;
typedef float  f4v    __attribute__((ext_vector_type(4)));
typedef short  short8 __attribute__((ext_vector_type(8)));
typedef __bf16 bf16x8 __attribute__((ext_vector_type(8)));

// ws layout (bytes):
//   W14B   @ 0          524288   (w1,w2,w3,w6 bf16)
//   WCATB  @ 524288     524288
//   W6P    @ 1048576    51380224 ([2048][12544] bf16, permuted k'=n*256+c)
//   W7B    @ 52428800   4194304  ([2][1024][1024] bf16)
//   BIAS6  @ 56623104   8192     ([2048] f32)
//   POOL   @ 56631296   104857600  ([204800][256] bf16)  -- XF overlays after convs
//   ATTN   @ 161488896  40140800   ([4096][2450] f32)    -- XC1 overlays after scat
//   Y      @ 201629696  104857600  ([204800][256] bf16)  -- PART (67MB f32) overlays after scat
// total = 306487296 bytes

__device__ __forceinline__ u16 f2bf(float f) {
  union { float f; u32 u; } v; v.f = f;
  return (u16)((v.u + 0x7FFFu + ((v.u >> 16) & 1u)) >> 16);
}

__device__ __forceinline__ int seg_gb(int k) { return (k == 0) ? 0 : (k == 1) ? 4096 : (k == 2) ? 20480 : 57344; }
__device__ __forceinline__ int seg_pc(int k) { return (k == 0) ? 1 : (k == 1) ? 4 : (k == 2) ? 9 : 36; }
__device__ __forceinline__ int seg_s0(int k) { return (k == 0) ? 0 : (k == 1) ? 1 : (k == 2) ? 5 : 14; }

// async global->LDS, 16B per lane; LDS dest = wave-uniform base + lane*16
__device__ __forceinline__ void gl16(const void* g, void* l) {
  __builtin_amdgcn_global_load_lds(
      (const __attribute__((address_space(1))) unsigned int*)g,
      (__attribute__((address_space(3))) unsigned int*)l, 16, 0, 0);
}

// ---------------- K0: pack / convert / permute weights ----------------
__global__ __launch_bounds__(256) void k_pack(
    const float* __restrict__ w1, const float* __restrict__ w2,
    const float* __restrict__ w3, const float* __restrict__ w6,
    const float* __restrict__ wcat,
    const float* __restrict__ f6c, const float* __restrict__ f6r,
    const float* __restrict__ f7c, const float* __restrict__ f7r,
    const float* __restrict__ b6c, const float* __restrict__ b6r,
    u16* __restrict__ W14B, u16* __restrict__ WCATB, u16* __restrict__ W6P,
    u16* __restrict__ W7B, float* __restrict__ BIAS6)
{
  const u32 total = 28313600u;
  for (u32 t = blockIdx.x * 256u + threadIdx.x; t < total; t += gridDim.x * 256u) {
    if (t < 262144u) {
      u32 a = t >> 16, i = t & 65535u;
      const float* s = (a == 0) ? w1 : (a == 1) ? w2 : (a == 2) ? w3 : w6;
      W14B[t] = f2bf(s[i]);
    } else if (t < 524288u) {
      u32 i = t - 262144u;
      WCATB[i] = f2bf(wcat[i]);
    } else if (t < 26214400u) {
      u32 j = t - 524288u;
      u32 r = j / 12544u, rem = j - r * 12544u;
      u32 n = rem >> 8, c = rem & 255u;  // out index = n*256 + c
      const float* s = (r < 1024u) ? f6c : f6r;
      W6P[j] = f2bf(s[(size_t)(r & 1023u) * 12544u + c * 49u + n]);
    } else if (t < 28311552u) {
      u32 j = t - 26214400u;
      W7B[j] = f2bf((j < 1048576u) ? f7c[j] : f7r[j - 1048576u]);
    } else {
      u32 j = t - 28311552u;
      BIAS6[j] = (j < 1024u) ? b6c[j] : b6r[j - 1024u];
    }
  }
}

// ---------------- K1: per-sample pooled + scores + softmax ----------------
#define XST 260
#define SST 52

__device__ __forceinline__ void pool_geom(int p, int& k, int& pl, int& r0, int& nr, int& c0, int& nc) {
  if (p == 0)      { k = 0; pl = 0;      r0 = 0; nr = 7; c0 = 0; nc = 7; }
  else if (p < 5)  { k = 1; pl = p - 1;  int i = pl >> 1, j = pl & 1; r0 = i * 3; nr = 4; c0 = j * 3; nc = 4; }
  else if (p < 14) { k = 2; pl = p - 5;  int i = pl / 3,  j = pl % 3; r0 = i * 2; nr = 3; c0 = j * 2; nc = 3; }
  else             { k = 3; pl = p - 14; int i = pl / 6,  j = pl % 6; r0 = i;     nr = 2; c0 = j;     nc = 2; }
}

__global__ __launch_bounds__(1024) void k_pool_attn(
    const float* __restrict__ x, u16* __restrict__ POOL, float* __restrict__ ATTN)
{
  __shared__ float XsT[49 * XST];  // [n][c]
  __shared__ float PsT[50 * XST];  // [p][c]
  __shared__ float Ss[49 * SST];   // [n][p]
  const int b = blockIdx.x;
  const int t = threadIdx.x;
  const float* xb = x + (size_t)b * 12544;

  for (int j = t; j < 12544; j += 1024) {
    int c = j / 49, n = j - c * 49;
    XsT[n * XST + c] = xb[j];
  }
  __syncthreads();

  for (int j = t; j < 12800; j += 1024) {
    int p = j >> 8, c = j & 255;
    int k, pl, r0, nr, c0, nc;
    pool_geom(p, k, pl, r0, nr, c0, nc);
    float s = 0.f;
    for (int r = 0; r < nr; ++r)
      for (int q = 0; q < nc; ++q)
        s += XsT[((r0 + r) * 7 + c0 + q) * XST + c];
    s *= (1.0f / (float)(nr * nc));
    PsT[p * XST + c] = s;
    POOL[((size_t)(seg_gb(k) + b * seg_pc(k) + pl)) * 256 + c] = f2bf(s);
  }
  __syncthreads();

  for (int pr = t; pr < 2450; pr += 1024) {
    int n = pr / 50, p = pr - n * 50;
    const f4v* xr = (const f4v*)(XsT + n * XST);
    const f4v* pq = (const f4v*)(PsT + p * XST);
    float s = 0.f;
    #pragma unroll 8
    for (int i = 0; i < 64; ++i) {
      f4v a = xr[i], bb = pq[i];
      s += a[0] * bb[0] + a[1] * bb[1] + a[2] * bb[2] + a[3] * bb[3];
    }
    Ss[n * SST + p] = s;
  }
  __syncthreads();

  if (t < 196) {
    int n = t >> 2, k = t & 3;
    int s0 = seg_s0(k), pc = seg_pc(k);
    float m = -3.0e38f;
    for (int i = 0; i < pc; ++i) m = fmaxf(m, Ss[n * SST + s0 + i]);
    float sum = 0.f;
    for (int i = 0; i < pc; ++i) sum += __expf(Ss[n * SST + s0 + i] - m);
    float inv = 1.0f / sum;
    float* ab = ATTN + (size_t)b * 2450 + n * 50 + s0;
    for (int i = 0; i < pc; ++i) ab[i] = __expf(Ss[n * SST + s0 + i] - m) * inv;
  }
}

// ---------------- K3': per-sample scat = relu(attn@Y), then xf = x + wcat@scat ----------------
#define SCO 1032

__global__ __launch_bounds__(512) void k_scat_conv(
    const u16* __restrict__ Y, const float* __restrict__ ATTN,
    const u16* __restrict__ WCATB, const float* __restrict__ x,
    u16* __restrict__ XF)
{
  __shared__ u16 scatT[64 * SCO];  // [n(pad64)][o 0..1023], bf16
  __shared__ float attnS[2450];
  const int b = blockIdx.x;
  const int t = threadIdx.x;

  for (int i = t; i < 2450; i += 512) attnS[i] = ATTN[(size_t)b * 2450 + i];
  {
    u32* z = (u32*)(scatT + 49 * SCO);
    for (int i = t; i < 7740; i += 512) z[i] = 0u;  // zero rows 49..63
  }
  __syncthreads();

  for (int task = t; task < 3136; task += 512) {  // 49 n * 64 o-chunks
    int n = task % 49, oc = task / 49;
    int k = oc >> 4;
    int c16 = (oc & 15) * 16;
    int pc = seg_pc(k), s0 = seg_s0(k), gb = seg_gb(k);
    const u16* ybase = Y + ((size_t)(gb + b * pc)) * 256 + c16;
    float s[16];
    #pragma unroll
    for (int j = 0; j < 16; ++j) s[j] = 0.f;
    for (int p = 0; p < pc; ++p) {
      float a = attnS[n * 50 + s0 + p];
      const u16* yp = ybase + (size_t)p * 256;
      u32 yw[8];
      *(int4*)(&yw[0]) = *(const int4*)(yp);
      *(int4*)(&yw[4]) = *(const int4*)(yp + 8);
      #pragma unroll
      for (int j = 0; j < 8; ++j) {
        union { u32 u; float f; } lo, hi;
        lo.u = (yw[j] & 0xFFFFu) << 16;
        hi.u = yw[j] & 0xFFFF0000u;
        s[2 * j]     += a * lo.f;
        s[2 * j + 1] += a * hi.f;
      }
    }
    u16 ov[16];
    #pragma unroll
    for (int j = 0; j < 16; ++j) ov[j] = f2bf(fmaxf(s[j], 0.f));
    *(int4*)(&scatT[n * SCO + oc * 16])     = *(const int4*)(&ov[0]);
    *(int4*)(&scatT[n * SCO + oc * 16 + 8]) = *(const int4*)(&ov[8]);
  }
  __syncthreads();

  // MFMA: XF[n][c] = x[b][c][n] + sum_o scatT[n][o] * wcat[c][o]
  const int l = t & 63, w = t >> 6;
  const int lr = l & 15, lg = l >> 4;
  f4v acc[4][2] = {};
  for (int ks = 0; ks < 32; ++ks) {
    int o0 = ks * 32;
    short8 af[4];
    short8 bfv[2];
    #pragma unroll
    for (int mi = 0; mi < 4; ++mi) {
      int n = mi * 16 + lr;
      af[mi] = *(const short8*)(&scatT[n * SCO + o0 + lg * 8]);
    }
    #pragma unroll
    for (int cc = 0; cc < 2; ++cc) {
      int c = (w * 2 + cc) * 16 + lr;
      bfv[cc] = *(const short8*)(WCATB + (size_t)c * 1024 + o0 + lg * 8);
    }
    #pragma unroll
    for (int mi = 0; mi < 4; ++mi)
      #pragma unroll
      for (int cc = 0; cc < 2; ++cc)
        acc[mi][cc] = __builtin_amdgcn_mfma_f32_16x16x32_bf16(
            __builtin_bit_cast(bf16x8, af[mi]),
            __builtin_bit_cast(bf16x8, bfv[cc]),
            acc[mi][cc], 0, 0, 0);
  }
  #pragma unroll
  for (int mi = 0; mi < 4; ++mi) {
    #pragma unroll
    for (int cc = 0; cc < 2; ++cc) {
      int c = (w * 2 + cc) * 16 + lr;
      #pragma unroll
      for (int j = 0; j < 4; ++j) {
        int n = mi * 16 + lg * 4 + j;
        if (n < 49) {
          float v = acc[mi][cc][j] + x[(size_t)b * 12544 + (size_t)c * 49 + n];
          XF[((size_t)b * 49 + n) * 256 + c] = f2bf(v);
        }
      }
    }
  }
}

// ---------------- 128x128 bf16 MFMA GEMM, m97-structure ----------------
// global_load_lds(16B) staging, pre-swizzled source + XOR-swizzled ds_read,
// XCD-chunked bijective swizzle + supercolumn raster, optional split-K.
template<bool OBF16>
__global__ __launch_bounds__(256) void gemm_k(
    const u16* __restrict__ A, int lda,
    const u16* __restrict__ W, int ldb,
    void* __restrict__ Cout, int ldc,
    int mtiles, int ntiles, int scW, int kchunk,
    const float* __restrict__ bias, int relu)
{
  __shared__ char lds[32768];
  char* ldsA = lds;
  char* ldsB = lds + 16384;
  const int tid = threadIdx.x;
  const int wv = tid >> 6, l = tid & 63;

  // bijective XCD swizzle (m204): same-XCD blocks -> contiguous wg
  const int nwg = gridDim.x;
  const int q = nwg >> 3, r8 = nwg & 7;
  const int xcd = blockIdx.x & 7, pos = blockIdx.x >> 3;
  int wg = (xcd < r8 ? xcd * (q + 1) : r8 * (q + 1) + (xcd - r8) * q) + pos;

  const int sub = mtiles * ntiles;
  const int ks = wg / sub; wg -= ks * sub;
  const int band = mtiles * scW;
  const int sc = wg / band; wg -= sc * band;
  const int mt = wg / scW;
  const int nt = sc * scW + (wg - mt * scW);
  const int m0 = mt * 128, n0 = nt * 128;
  const int k0 = ks * kchunk;

  const char* Ab = (const char*)(A + (size_t)m0 * lda + k0);
  const char* Bb = (const char*)(W + (size_t)n0 * ldb + k0);
  const int ldab = lda * 2, ldbb = ldb * 2;
  const int rloc = l >> 3;                    // row within 8-row group
  const int swz = ((l & 7) ^ rloc) << 4;      // pre-swizzled byte-in-row (involution)

  auto stage = [&](int kt) {
    const char* Ak = Ab + kt * 2 + swz;
    const char* Bk = Bb + kt * 2 + swz;
    #pragma unroll
    for (int it = 0; it < 4; ++it) {
      int rb = (it * 4 + wv) * 8;
      gl16(Ak + (size_t)(rb + rloc) * ldab, ldsA + rb * 128);
      gl16(Bk + (size_t)(rb + rloc) * ldbb, ldsB + rb * 128);
    }
  };

  const int wr = (wv >> 1) * 64, wc = (wv & 1) * 64;
  const int lr = l & 15, lg = l >> 4;
  f4v acc[4][4] = {};

  stage(0);
  for (int kt = 0; kt < kchunk; kt += 64) {
    __syncthreads();  // drains vmcnt: tile ready
    #pragma unroll
    for (int kk = 0; kk < 2; ++kk) {
      short8 af[4], bfv[4];
      #pragma unroll
      for (int mi = 0; mi < 4; ++mi) {
        int rA = wr + mi * 16 + lr;
        af[mi] = *(const short8*)(ldsA + rA * 128 + ((kk * 64 + lg * 16) ^ ((rA & 7) << 4)));
      }
      #pragma unroll
      for (int ni = 0; ni < 4; ++ni) {
        int rB = wc + ni * 16 + lr;
        bfv[ni] = *(const short8*)(ldsB + rB * 128 + ((kk * 64 + lg * 16) ^ ((rB & 7) << 4)));
      }
      #pragma unroll
      for (int mi = 0; mi < 4; ++mi)
        #pragma unroll
        for (int ni = 0; ni < 4; ++ni)
          acc[mi][ni] = __builtin_amdgcn_mfma_f32_16x16x32_bf16(
              __builtin_bit_cast(bf16x8, af[mi]),
              __builtin_bit_cast(bf16x8, bfv[ni]),
              acc[mi][ni], 0, 0, 0);
    }
    if (kt + 64 < kchunk) { __syncthreads(); stage(kt + 64); }
  }

  const size_t crow0 = (size_t)ks * mtiles * 128 + m0;
  #pragma unroll
  for (int ni = 0; ni < 4; ++ni) {
    int gc = n0 + wc + ni * 16 + lr;
    float bv = bias ? bias[gc] : 0.f;
    #pragma unroll
    for (int mi = 0; mi < 4; ++mi) {
      #pragma unroll
      for (int j = 0; j < 4; ++j) {
        size_t gr = crow0 + wr + mi * 16 + lg * 4 + j;
        float v = acc[mi][ni][j] + bv;
        if (relu) v = fmaxf(v, 0.f);
        if (OBF16) ((u16*)Cout)[gr * ldc + gc] = f2bf(v);
        else       ((float*)Cout)[gr * ldc + gc] = v;
      }
    }
  }
}

// ---------------- reduce split-K partials + bias + relu -> bf16 ----------------
__global__ __launch_bounds__(256) void k_red6(
    const float* __restrict__ P, const float* __restrict__ bias, u16* __restrict__ XC1)
{
  const size_t base = ((size_t)blockIdx.x * 256 + threadIdx.x) * 8;  // 8.4M elems
  f4v a0 = *(const f4v*)(P + base);
  f4v a1 = *(const f4v*)(P + base + 4);
  const float* P2 = P + 8388608;
  f4v b0 = *(const f4v*)(P2 + base);
  f4v b1 = *(const f4v*)(P2 + base + 4);
  int col = (int)(base & 2047u);
  u16 o[8];
  #pragma unroll
  for (int j = 0; j < 4; ++j) o[j]     = f2bf(fmaxf(a0[j] + b0[j] + bias[col + j], 0.f));
  #pragma unroll
  for (int j = 0; j < 4; ++j) o[4 + j] = f2bf(fmaxf(a1[j] + b1[j] + bias[col + 4 + j], 0.f));
  *(int4*)(XC1 + base) = *(const int4*)(&o[0]);
}

extern "C" void kernel_launch(void* const* d_in, const int* in_sizes, int n_in,
                              void* d_out, int out_size, void* d_ws, size_t ws_size,
                              hipStream_t stream)
{
  (void)in_sizes; (void)n_in; (void)out_size; (void)ws_size;
  const float* x    = (const float*)d_in[0];
  const float* w1   = (const float*)d_in[1];
  const float* w2   = (const float*)d_in[2];
  const float* w3   = (const float*)d_in[3];
  const float* w6   = (const float*)d_in[4];
  const float* wcat = (const float*)d_in[5];
  const float* f6cw = (const float*)d_in[6];
  const float* f6cb = (const float*)d_in[7];
  const float* f7cw = (const float*)d_in[8];
  const float* f7cb = (const float*)d_in[9];
  const float* f6rw = (const float*)d_in[10];
  const float* f6rb = (const float*)d_in[11];
  const float* f7rw = (const float*)d_in[12];
  const float* f7rb = (const float*)d_in[13];

  char* ws = (char*)d_ws;
  u16*   W14B  = (u16*)(ws);
  u16*   WCATB = (u16*)(ws + 524288);
  u16*   W6P   = (u16*)(ws + 1048576);
  u16*   W7B   = (u16*)(ws + 52428800);
  float* BIAS6 = (float*)(ws + 56623104);
  u16*   POOL  = (u16*)(ws + 56631296);
  u16*   XF    = POOL;                      // overlay: POOL dead after convs
  float* ATTN  = (float*)(ws + 161488896);
  u16*   XC1   = (u16*)(ws + 161488896);    // overlay: ATTN dead after scat
  u16*   Y     = (u16*)(ws + 201629696);
  float* PART  = (float*)(ws + 201629696);  // overlay: Y dead after scat (2x4096x2048 f32)

  k_pack<<<dim3(2048), dim3(256), 0, stream>>>(w1, w2, w3, w6, wcat, f6cw, f6rw,
                                               f7cw, f7rw, f6cb, f6rb,
                                               W14B, WCATB, W6P, W7B, BIAS6);
  k_pool_attn<<<dim3(4096), dim3(1024), 0, stream>>>(x, POOL, ATTN);

  for (int k = 0; k < 4; ++k) {
    int gb = (k == 0) ? 0 : (k == 1) ? 4096 : (k == 2) ? 20480 : 57344;
    int pc = (k == 0) ? 1 : (k == 1) ? 4 : (k == 2) ? 9 : 36;
    int mtl = 32 * pc;
    gemm_k<true><<<dim3(mtl * 2), dim3(256), 0, stream>>>(
        POOL + (size_t)gb * 256, 256, W14B + k * 65536, 256,
        (void*)(Y + (size_t)gb * 256), 256, mtl, 2, 2, 256, nullptr, 0);
  }

  k_scat_conv<<<dim3(4096), dim3(512), 0, stream>>>(Y, ATTN, WCATB, x, XF);

  // fc6 (fused c|r): M=4096, N=2048, K=12544, split-K=2 -> f32 partials
  gemm_k<false><<<dim3(1024), dim3(256), 0, stream>>>(
      XF, 12544, W6P, 12544, (void*)PART, 2048, 32, 16, 8, 6272, nullptr, 0);
  k_red6<<<dim3(4096), dim3(256), 0, stream>>>(PART, BIAS6, XC1);

  float* out = (float*)d_out;
  gemm_k<false><<<dim3(256), dim3(256), 0, stream>>>(
      XC1, 2048, W7B, 1024, (void*)out, 1024, 32, 8, 8, 1024, f7cb, 0);
  gemm_k<false><<<dim3(256), dim3(256), 0, stream>>>(
      XC1 + 1024, 2048, W7B + 1048576, 1024,
      (void*)(out + (size_t)4096 * 1024), 1024, 32, 8, 8, 1024, f7rb, 1);
}

// Round 6
// 1909.530 us; speedup vs baseline: 1.6216x; 1.0940x over previous
//
#include <hip/hip_runtime.h>

typedef unsigned short u16;
typedef unsigned int   u32;
typedef float  f4v    __attribute__((ext_vector_type(4)));
typedef short  short8 __attribute__((ext_vector_type(8)));
typedef __bf16 bf16x8 __attribute__((ext_vector_type(8)));

// ws layout (bytes):
//   W14B   @ 0          524288   (w1,w2,w3,w6 bf16)
//   WCATB  @ 524288     524288
//   W6P    @ 1048576    51380224 ([2048][12544] bf16, permuted k'=n*256+c)
//   W7B    @ 52428800   4194304  ([2][1024][1024] bf16)
//   BIAS6  @ 56623104   8192     ([2048] f32)
//   POOL   @ 56631296   104857600  ([204800][256] bf16)  -- XF overlays after convs
//   ATTN   @ 161488896  40140800   ([4096][2450] f32)    -- XC1 overlays after scat
//   Y      @ 201629696  104857600  ([204800][256] bf16)  -- PART (67MB f32) overlays after scat
// total = 306487296 bytes

__device__ __forceinline__ u16 f2bf(float f) {
  union { float f; u32 u; } v; v.f = f;
  return (u16)((v.u + 0x7FFFu + ((v.u >> 16) & 1u)) >> 16);
}

__device__ __forceinline__ int seg_gb(int k) { return (k == 0) ? 0 : (k == 1) ? 4096 : (k == 2) ? 20480 : 57344; }
__device__ __forceinline__ int seg_pc(int k) { return (k == 0) ? 1 : (k == 1) ? 4 : (k == 2) ? 9 : 36; }
__device__ __forceinline__ int seg_s0(int k) { return (k == 0) ? 0 : (k == 1) ? 1 : (k == 2) ? 5 : 14; }

// async global->LDS, 16B per lane; LDS dest = wave-uniform base + lane*16
__device__ __forceinline__ void gl16(const void* g, void* l) {
  __builtin_amdgcn_global_load_lds(
      (const __attribute__((address_space(1))) unsigned int*)g,
      (__attribute__((address_space(3))) unsigned int*)l, 16, 0, 0);
}

// ---------------- K0: pack / convert / permute weights ----------------
__global__ __launch_bounds__(256) void k_pack(
    const float* __restrict__ w1, const float* __restrict__ w2,
    const float* __restrict__ w3, const float* __restrict__ w6,
    const float* __restrict__ wcat,
    const float* __restrict__ f6c, const float* __restrict__ f6r,
    const float* __restrict__ f7c, const float* __restrict__ f7r,
    const float* __restrict__ b6c, const float* __restrict__ b6r,
    u16* __restrict__ W14B, u16* __restrict__ WCATB, u16* __restrict__ W6P,
    u16* __restrict__ W7B, float* __restrict__ BIAS6)
{
  const u32 total = 28313600u;
  for (u32 t = blockIdx.x * 256u + threadIdx.x; t < total; t += gridDim.x * 256u) {
    if (t < 262144u) {
      u32 a = t >> 16, i = t & 65535u;
      const float* s = (a == 0) ? w1 : (a == 1) ? w2 : (a == 2) ? w3 : w6;
      W14B[t] = f2bf(s[i]);
    } else if (t < 524288u) {
      u32 i = t - 262144u;
      WCATB[i] = f2bf(wcat[i]);
    } else if (t < 26214400u) {
      u32 j = t - 524288u;
      u32 r = j / 12544u, rem = j - r * 12544u;
      u32 n = rem >> 8, c = rem & 255u;  // out index = n*256 + c
      const float* s = (r < 1024u) ? f6c : f6r;
      W6P[j] = f2bf(s[(size_t)(r & 1023u) * 12544u + c * 49u + n]);
    } else if (t < 28311552u) {
      u32 j = t - 26214400u;
      W7B[j] = f2bf((j < 1048576u) ? f7c[j] : f7r[j - 1048576u]);
    } else {
      u32 j = t - 28311552u;
      BIAS6[j] = (j < 1024u) ? b6c[j] : b6r[j - 1024u];
    }
  }
}

// ---------------- K1: per-sample pooled + scores + softmax ----------------
#define XST 260
#define SST 52

__device__ __forceinline__ void pool_geom(int p, int& k, int& pl, int& r0, int& nr, int& c0, int& nc) {
  if (p == 0)      { k = 0; pl = 0;      r0 = 0; nr = 7; c0 = 0; nc = 7; }
  else if (p < 5)  { k = 1; pl = p - 1;  int i = pl >> 1, j = pl & 1; r0 = i * 3; nr = 4; c0 = j * 3; nc = 4; }
  else if (p < 14) { k = 2; pl = p - 5;  int i = pl / 3,  j = pl % 3; r0 = i * 2; nr = 3; c0 = j * 2; nc = 3; }
  else             { k = 3; pl = p - 14; int i = pl / 6,  j = pl % 6; r0 = i;     nr = 2; c0 = j;     nc = 2; }
}

__global__ __launch_bounds__(1024) void k_pool_attn(
    const float* __restrict__ x, u16* __restrict__ POOL, float* __restrict__ ATTN)
{
  __shared__ float XsT[49 * XST];  // [n][c]
  __shared__ float PsT[50 * XST];  // [p][c]
  __shared__ float Ss[49 * SST];   // [n][p]
  const int b = blockIdx.x;
  const int t = threadIdx.x;
  const float* xb = x + (size_t)b * 12544;

  for (int j = t; j < 12544; j += 1024) {
    int c = j / 49, n = j - c * 49;
    XsT[n * XST + c] = xb[j];
  }
  __syncthreads();

  for (int j = t; j < 12800; j += 1024) {
    int p = j >> 8, c = j & 255;
    int k, pl, r0, nr, c0, nc;
    pool_geom(p, k, pl, r0, nr, c0, nc);
    float s = 0.f;
    for (int r = 0; r < nr; ++r)
      for (int q = 0; q < nc; ++q)
        s += XsT[((r0 + r) * 7 + c0 + q) * XST + c];
    s *= (1.0f / (float)(nr * nc));
    PsT[p * XST + c] = s;
    POOL[((size_t)(seg_gb(k) + b * seg_pc(k) + pl)) * 256 + c] = f2bf(s);
  }
  __syncthreads();

  for (int pr = t; pr < 2450; pr += 1024) {
    int n = pr / 50, p = pr - n * 50;
    const f4v* xr = (const f4v*)(XsT + n * XST);
    const f4v* pq = (const f4v*)(PsT + p * XST);
    float s = 0.f;
    #pragma unroll 8
    for (int i = 0; i < 64; ++i) {
      f4v a = xr[i], bb = pq[i];
      s += a[0] * bb[0] + a[1] * bb[1] + a[2] * bb[2] + a[3] * bb[3];
    }
    Ss[n * SST + p] = s;
  }
  __syncthreads();

  if (t < 196) {
    int n = t >> 2, k = t & 3;
    int s0 = seg_s0(k), pc = seg_pc(k);
    float m = -3.0e38f;
    for (int i = 0; i < pc; ++i) m = fmaxf(m, Ss[n * SST + s0 + i]);
    float sum = 0.f;
    for (int i = 0; i < pc; ++i) sum += __expf(Ss[n * SST + s0 + i] - m);
    float inv = 1.0f / sum;
    float* ab = ATTN + (size_t)b * 2450 + n * 50 + s0;
    for (int i = 0; i < pc; ++i) ab[i] = __expf(Ss[n * SST + s0 + i] - m) * inv;
  }
}

// ---------------- K3' v2: per-sample MFMA scat + conv + residual ----------------
// Stage A (per tier k, per 128-col half): scatCh[64 n][128 o'] = relu(attn_k @ Y_k)
// Stage B: acc[n][c] += scatCh @ WCATB[c][k*256+h*128+o']   (K-reduced over all o)
// Epilogue: XF[n][c] = acc + xS[n][c]
// LDS = 5.1 + 25.9 + 32 + 16 = ~79 KB -> 2 blocks/CU.
__global__ __launch_bounds__(512, 4) void k_scat_conv(
    const u16* __restrict__ Y, const float* __restrict__ ATTN,
    const u16* __restrict__ WCATB, const float* __restrict__ x,
    u16* __restrict__ XF)
{
  __shared__ __align__(16) u16 attnB[49 * 52];    // [n][p] bf16, stride 52
  __shared__ __align__(16) u16 xS[49 * 264];      // [n][c] bf16, stride 264
  __shared__ __align__(16) u16 YT[256 * 64];      // [c][p] bf16, sigma-swizzled
  __shared__ __align__(16) u16 scatCh[64 * 128];  // [n][o'] bf16, swizzled
  const int b = blockIdx.x;
  const int t = threadIdx.x;
  const int wv = t >> 6, l = t & 63;
  const int lr = l & 15, lg = l >> 4;

  // prologue staging
  for (int i = t; i < 2450; i += 512) {
    int n = i / 50, p = i - n * 50;
    attnB[n * 52 + p] = f2bf(ATTN[(size_t)b * 2450 + i]);
  }
  for (int i = t; i < 12544; i += 512) {
    int c = i / 49, n = i - c * 49;
    xS[n * 264 + c] = f2bf(x[(size_t)b * 12544 + i]);
  }
  {
    int4 zz; zz.x = 0; zz.y = 0; zz.z = 0; zz.w = 0;
    int4* z = (int4*)YT;
    #pragma unroll
    for (int i = 0; i < 4; ++i) z[t + i * 512] = zz;  // zero all 64 p-rows once
  }
  __syncthreads();

  f4v acc[4][2] = {};

  for (int k = 0; k < 4; ++k) {
    const int pc = seg_pc(k), s0 = seg_s0(k), gb = seg_gb(k);
    const int kks = (k == 3) ? 2 : 1;

    // restage YT rows [0,pc): tiers ascend in pc, so rows >= pc stay zero
    for (int i = t; i < pc * 256; i += 512) {
      int p = i >> 8, c = i & 255;
      u32 sig = (u32)(((c & 7) ^ ((c >> 3) & 7)) << 4);
      u16 v = Y[((size_t)(gb + b * pc + p)) * 256 + c];
      *(u16*)((char*)YT + c * 128 + ((2u * p) ^ sig)) = v;
    }
    __syncthreads();

    for (int h = 0; h < 2; ++h) {
      // ---- stage A: scat chunk for c' in [h*128, h*128+128) ----
      {
        const int cB = h * 128 + wv * 16 + lr;
        const u32 sig = (u32)(((cB & 7) ^ ((cB >> 3) & 7)) << 4);
        f4v sacc[4] = {};
        for (int kk = 0; kk < kks; ++kk) {
          short8 bfv = *(const short8*)((const char*)YT + cB * 128 + (((u32)(kk * 64 + lg * 16)) ^ sig));
          #pragma unroll
          for (int mi = 0; mi < 4; ++mi) {
            int n = mi * 16 + lr;
            short8 af;
            #pragma unroll
            for (int j = 0; j < 8; ++j) {
              int p = kk * 32 + lg * 8 + j;
              u16 v = attnB[(n < 49 ? n : 0) * 52 + s0 + (p < pc ? p : 0)];
              af[j] = (n < 49 && p < pc) ? (short)v : (short)0;
            }
            sacc[mi] = __builtin_amdgcn_mfma_f32_16x16x32_bf16(
                __builtin_bit_cast(bf16x8, af), __builtin_bit_cast(bf16x8, bfv),
                sacc[mi], 0, 0, 0);
          }
        }
        #pragma unroll
        for (int mi = 0; mi < 4; ++mi) {
          #pragma unroll
          for (int r = 0; r < 4; ++r) {
            int n = mi * 16 + lg * 4 + r;
            int op = wv * 16 + lr;
            *(u16*)((char*)scatCh + n * 256 + ((2u * op) ^ (u32)((n & 7) << 4))) =
                f2bf(fmaxf(sacc[mi][r], 0.f));
          }
        }
      }
      __syncthreads();
      // ---- stage B: acc += scatCh @ WCATB slice ----
      {
        #pragma unroll
        for (int kk = 0; kk < 4; ++kk) {
          short8 af2[4];
          #pragma unroll
          for (int mi = 0; mi < 4; ++mi) {
            int n = mi * 16 + lr;
            af2[mi] = *(const short8*)((const char*)scatCh + n * 256 +
                        (((u32)(kk * 64 + lg * 16)) ^ (u32)((n & 7) << 4)));
          }
          #pragma unroll
          for (int ni = 0; ni < 2; ++ni) {
            int c = wv * 32 + ni * 16 + lr;
            short8 bf2 = *(const short8*)(WCATB + (size_t)c * 1024 +
                          k * 256 + h * 128 + kk * 32 + lg * 8);
            #pragma unroll
            for (int mi = 0; mi < 4; ++mi)
              acc[mi][ni] = __builtin_amdgcn_mfma_f32_16x16x32_bf16(
                  __builtin_bit_cast(bf16x8, af2[mi]), __builtin_bit_cast(bf16x8, bf2),
                  acc[mi][ni], 0, 0, 0);
          }
        }
      }
      __syncthreads();
    }
  }

  // epilogue: XF[n][c] = acc + x (from xS)
  #pragma unroll
  for (int mi = 0; mi < 4; ++mi) {
    #pragma unroll
    for (int r = 0; r < 4; ++r) {
      int n = mi * 16 + lg * 4 + r;
      if (n < 49) {
        #pragma unroll
        for (int ni = 0; ni < 2; ++ni) {
          int c = wv * 32 + ni * 16 + lr;
          union { u32 u; float f; } xv; xv.u = (u32)xS[n * 264 + c] << 16;
          XF[((size_t)b * 49 + n) * 256 + c] = f2bf(acc[mi][ni][r] + xv.f);
        }
      }
    }
  }
}

// ---------------- 128x128 bf16 MFMA GEMM, m97-structure ----------------
template<bool OBF16>
__global__ __launch_bounds__(256) void gemm_k(
    const u16* __restrict__ A, int lda,
    const u16* __restrict__ W, int ldb,
    void* __restrict__ Cout, int ldc,
    int mtiles, int ntiles, int scW, int kchunk,
    const float* __restrict__ bias, int relu)
{
  __shared__ char lds[32768];
  char* ldsA = lds;
  char* ldsB = lds + 16384;
  const int tid = threadIdx.x;
  const int wv = tid >> 6, l = tid & 63;

  // bijective XCD swizzle (m204): same-XCD blocks -> contiguous wg
  const int nwg = gridDim.x;
  const int q = nwg >> 3, r8 = nwg & 7;
  const int xcd = blockIdx.x & 7, pos = blockIdx.x >> 3;
  int wg = (xcd < r8 ? xcd * (q + 1) : r8 * (q + 1) + (xcd - r8) * q) + pos;

  const int sub = mtiles * ntiles;
  const int ks = wg / sub; wg -= ks * sub;
  const int band = mtiles * scW;
  const int sc = wg / band; wg -= sc * band;
  const int mt = wg / scW;
  const int nt = sc * scW + (wg - mt * scW);
  const int m0 = mt * 128, n0 = nt * 128;
  const int k0 = ks * kchunk;

  const char* Ab = (const char*)(A + (size_t)m0 * lda + k0);
  const char* Bb = (const char*)(W + (size_t)n0 * ldb + k0);
  const int ldab = lda * 2, ldbb = ldb * 2;
  const int rloc = l >> 3;                    // row within 8-row group
  const int swz = ((l & 7) ^ rloc) << 4;      // pre-swizzled byte-in-row (involution)

  auto stage = [&](int kt) {
    const char* Ak = Ab + kt * 2 + swz;
    const char* Bk = Bb + kt * 2 + swz;
    #pragma unroll
    for (int it = 0; it < 4; ++it) {
      int rb = (it * 4 + wv) * 8;
      gl16(Ak + (size_t)(rb + rloc) * ldab, ldsA + rb * 128);
      gl16(Bk + (size_t)(rb + rloc) * ldbb, ldsB + rb * 128);
    }
  };

  const int wr = (wv >> 1) * 64, wc = (wv & 1) * 64;
  const int lr = l & 15, lg = l >> 4;
  f4v acc[4][4] = {};

  stage(0);
  for (int kt = 0; kt < kchunk; kt += 64) {
    __syncthreads();  // drains vmcnt: tile ready
    #pragma unroll
    for (int kk = 0; kk < 2; ++kk) {
      short8 af[4], bfv[4];
      #pragma unroll
      for (int mi = 0; mi < 4; ++mi) {
        int rA = wr + mi * 16 + lr;
        af[mi] = *(const short8*)(ldsA + rA * 128 + ((kk * 64 + lg * 16) ^ ((rA & 7) << 4)));
      }
      #pragma unroll
      for (int ni = 0; ni < 4; ++ni) {
        int rB = wc + ni * 16 + lr;
        bfv[ni] = *(const short8*)(ldsB + rB * 128 + ((kk * 64 + lg * 16) ^ ((rB & 7) << 4)));
      }
      #pragma unroll
      for (int mi = 0; mi < 4; ++mi)
        #pragma unroll
        for (int ni = 0; ni < 4; ++ni)
          acc[mi][ni] = __builtin_amdgcn_mfma_f32_16x16x32_bf16(
              __builtin_bit_cast(bf16x8, af[mi]),
              __builtin_bit_cast(bf16x8, bfv[ni]),
              acc[mi][ni], 0, 0, 0);
    }
    if (kt + 64 < kchunk) { __syncthreads(); stage(kt + 64); }
  }

  const size_t crow0 = (size_t)ks * mtiles * 128 + m0;
  #pragma unroll
  for (int ni = 0; ni < 4; ++ni) {
    int gc = n0 + wc + ni * 16 + lr;
    float bv = bias ? bias[gc] : 0.f;
    #pragma unroll
    for (int mi = 0; mi < 4; ++mi) {
      #pragma unroll
      for (int j = 0; j < 4; ++j) {
        size_t gr = crow0 + wr + mi * 16 + lg * 4 + j;
        float v = acc[mi][ni][j] + bv;
        if (relu) v = fmaxf(v, 0.f);
        if (OBF16) ((u16*)Cout)[gr * ldc + gc] = f2bf(v);
        else       ((float*)Cout)[gr * ldc + gc] = v;
      }
    }
  }
}

// ---------------- reduce split-K partials + bias + relu -> bf16 ----------------
__global__ __launch_bounds__(256) void k_red6(
    const float* __restrict__ P, const float* __restrict__ bias, u16* __restrict__ XC1)
{
  const size_t base = ((size_t)blockIdx.x * 256 + threadIdx.x) * 8;  // 8.4M elems
  f4v a0 = *(const f4v*)(P + base);
  f4v a1 = *(const f4v*)(P + base + 4);
  const float* P2 = P + 8388608;
  f4v b0 = *(const f4v*)(P2 + base);
  f4v b1 = *(const f4v*)(P2 + base + 4);
  int col = (int)(base & 2047u);
  u16 o[8];
  #pragma unroll
  for (int j = 0; j < 4; ++j) o[j]     = f2bf(fmaxf(a0[j] + b0[j] + bias[col + j], 0.f));
  #pragma unroll
  for (int j = 0; j < 4; ++j) o[4 + j] = f2bf(fmaxf(a1[j] + b1[j] + bias[col + 4 + j], 0.f));
  *(int4*)(XC1 + base) = *(const int4*)(&o[0]);
}

extern "C" void kernel_launch(void* const* d_in, const int* in_sizes, int n_in,
                              void* d_out, int out_size, void* d_ws, size_t ws_size,
                              hipStream_t stream)
{
  (void)in_sizes; (void)n_in; (void)out_size; (void)ws_size;
  const float* x    = (const float*)d_in[0];
  const float* w1   = (const float*)d_in[1];
  const float* w2   = (const float*)d_in[2];
  const float* w3   = (const float*)d_in[3];
  const float* w6   = (const float*)d_in[4];
  const float* wcat = (const float*)d_in[5];
  const float* f6cw = (const float*)d_in[6];
  const float* f6cb = (const float*)d_in[7];
  const float* f7cw = (const float*)d_in[8];
  const float* f7cb = (const float*)d_in[9];
  const float* f6rw = (const float*)d_in[10];
  const float* f6rb = (const float*)d_in[11];
  const float* f7rw = (const float*)d_in[12];
  const float* f7rb = (const float*)d_in[13];

  char* ws = (char*)d_ws;
  u16*   W14B  = (u16*)(ws);
  u16*   WCATB = (u16*)(ws + 524288);
  u16*   W6P   = (u16*)(ws + 1048576);
  u16*   W7B   = (u16*)(ws + 52428800);
  float* BIAS6 = (float*)(ws + 56623104);
  u16*   POOL  = (u16*)(ws + 56631296);
  u16*   XF    = POOL;                      // overlay: POOL dead after convs
  float* ATTN  = (float*)(ws + 161488896);
  u16*   XC1   = (u16*)(ws + 161488896);    // overlay: ATTN dead after scat
  u16*   Y     = (u16*)(ws + 201629696);
  float* PART  = (float*)(ws + 201629696);  // overlay: Y dead after scat (2x4096x2048 f32)

  k_pack<<<dim3(2048), dim3(256), 0, stream>>>(w1, w2, w3, w6, wcat, f6cw, f6rw,
                                               f7cw, f7rw, f6cb, f6rb,
                                               W14B, WCATB, W6P, W7B, BIAS6);
  k_pool_attn<<<dim3(4096), dim3(1024), 0, stream>>>(x, POOL, ATTN);

  for (int k = 0; k < 4; ++k) {
    int gb = (k == 0) ? 0 : (k == 1) ? 4096 : (k == 2) ? 20480 : 57344;
    int pc = (k == 0) ? 1 : (k == 1) ? 4 : (k == 2) ? 9 : 36;
    int mtl = 32 * pc;
    gemm_k<true><<<dim3(mtl * 2), dim3(256), 0, stream>>>(
        POOL + (size_t)gb * 256, 256, W14B + k * 65536, 256,
        (void*)(Y + (size_t)gb * 256), 256, mtl, 2, 2, 256, nullptr, 0);
  }

  k_scat_conv<<<dim3(4096), dim3(512), 0, stream>>>(Y, ATTN, WCATB, x, XF);

  // fc6 (fused c|r): M=4096, N=2048, K=12544, split-K=2 -> f32 partials
  gemm_k<false><<<dim3(1024), dim3(256), 0, stream>>>(
      XF, 12544, W6P, 12544, (void*)PART, 2048, 32, 16, 8, 6272, nullptr, 0);
  k_red6<<<dim3(4096), dim3(256), 0, stream>>>(PART, BIAS6, XC1);

  float* out = (float*)d_out;
  gemm_k<false><<<dim3(256), dim3(256), 0, stream>>>(
      XC1, 2048, W7B, 1024, (void*)out, 1024, 32, 8, 8, 1024, f7cb, 0);
  gemm_k<false><<<dim3(256), dim3(256), 0, stream>>>(
      XC1 + 1024, 2048, W7B + 1048576, 1024,
      (void*)(out + (size_t)4096 * 1024), 1024, 32, 8, 8, 1024, f7rb, 1);
}

// Round 7
// 1775.697 us; speedup vs baseline: 1.7438x; 1.0754x over previous
//
#include <hip/hip_runtime.h>

typedef unsigned short u16;
typedef unsigned int   u32;
typedef float  f4v    __attribute__((ext_vector_type(4)));
typedef short  short8 __attribute__((ext_vector_type(8)));
typedef __bf16 bf16x8 __attribute__((ext_vector_type(8)));

// ws layout (bytes):
//   W14B   @ 0          524288   (w1,w2,w3,w6 bf16)
//   WCATB  @ 524288     524288
//   W6P    @ 1048576    51380224 ([2048][12544] bf16, permuted k'=n*256+c)
//   W7B    @ 52428800   4194304  ([2][1024][1024] bf16)
//   BIAS6  @ 56623104   8192     ([2048] f32)
//   POOL   @ 56631296   104857600  ([204800][256] bf16)  -- XF overlays after convs
//   ATTN   @ 161488896  40140800   ([4096][2450] f32)    -- XC1 overlays after scat
//   Y      @ 201629696  104857600  ([204800][256] bf16)  -- PART (67MB f32) overlays after scat
// total = 306487296 bytes

__device__ __forceinline__ u16 f2bf(float f) {
  union { float f; u32 u; } v; v.f = f;
  return (u16)((v.u + 0x7FFFu + ((v.u >> 16) & 1u)) >> 16);
}
__device__ __forceinline__ float bf2f(u16 h) {
  union { u32 u; float f; } v; v.u = (u32)h << 16;
  return v.f;
}

__device__ __forceinline__ int seg_gb(int k) { return (k == 0) ? 0 : (k == 1) ? 4096 : (k == 2) ? 20480 : 57344; }
__device__ __forceinline__ int seg_pc(int k) { return (k == 0) ? 1 : (k == 1) ? 4 : (k == 2) ? 9 : 36; }
__device__ __forceinline__ int seg_s0(int k) { return (k == 0) ? 0 : (k == 1) ? 1 : (k == 2) ? 5 : 14; }

// async global->LDS, 16B per lane; LDS dest = wave-uniform base + lane*16
__device__ __forceinline__ void gl16(const void* g, void* l) {
  __builtin_amdgcn_global_load_lds(
      (const __attribute__((address_space(1))) unsigned int*)g,
      (__attribute__((address_space(3))) unsigned int*)l, 16, 0, 0);
}

// ---------------- K0: pack / convert / permute weights ----------------
__global__ __launch_bounds__(256) void k_pack(
    const float* __restrict__ w1, const float* __restrict__ w2,
    const float* __restrict__ w3, const float* __restrict__ w6,
    const float* __restrict__ wcat,
    const float* __restrict__ f6c, const float* __restrict__ f6r,
    const float* __restrict__ f7c, const float* __restrict__ f7r,
    const float* __restrict__ b6c, const float* __restrict__ b6r,
    u16* __restrict__ W14B, u16* __restrict__ WCATB, u16* __restrict__ W6P,
    u16* __restrict__ W7B, float* __restrict__ BIAS6)
{
  const u32 total = 28313600u;
  for (u32 t = blockIdx.x * 256u + threadIdx.x; t < total; t += gridDim.x * 256u) {
    if (t < 262144u) {
      u32 a = t >> 16, i = t & 65535u;
      const float* s = (a == 0) ? w1 : (a == 1) ? w2 : (a == 2) ? w3 : w6;
      W14B[t] = f2bf(s[i]);
    } else if (t < 524288u) {
      u32 i = t - 262144u;
      WCATB[i] = f2bf(wcat[i]);
    } else if (t < 26214400u) {
      u32 j = t - 524288u;
      u32 r = j / 12544u, rem = j - r * 12544u;
      u32 n = rem >> 8, c = rem & 255u;  // out index = n*256 + c
      const float* s = (r < 1024u) ? f6c : f6r;
      W6P[j] = f2bf(s[(size_t)(r & 1023u) * 12544u + c * 49u + n]);
    } else if (t < 28311552u) {
      u32 j = t - 26214400u;
      W7B[j] = f2bf((j < 1048576u) ? f7c[j] : f7r[j - 1048576u]);
    } else {
      u32 j = t - 28311552u;
      BIAS6[j] = (j < 1024u) ? b6c[j] : b6r[j - 1024u];
    }
  }
}

// ---------------- K1 v2: pooled + MFMA scores (hi/lo bf16) + softmax ----------------
#define PST 272   // u16 row stride: 544B = 136 words == 8 mod 32 -> even bank spread
#define SST 52

__device__ __forceinline__ void pool_geom(int p, int& k, int& pl, int& r0, int& nr, int& c0, int& nc) {
  if (p == 0)      { k = 0; pl = 0;      r0 = 0; nr = 7; c0 = 0; nc = 7; }
  else if (p < 5)  { k = 1; pl = p - 1;  int i = pl >> 1, j = pl & 1; r0 = i * 3; nr = 4; c0 = j * 3; nc = 4; }
  else if (p < 14) { k = 2; pl = p - 5;  int i = pl / 3,  j = pl % 3; r0 = i * 2; nr = 3; c0 = j * 2; nc = 3; }
  else             { k = 3; pl = p - 14; int i = pl / 6,  j = pl % 6; r0 = i;     nr = 2; c0 = j;     nc = 2; }
}

__global__ __launch_bounds__(1024) void k_pool_attn(
    const float* __restrict__ x, u16* __restrict__ POOL, float* __restrict__ ATTN)
{
  __shared__ __align__(16) u16 Xh[49 * PST];  // [n][c] bf16 hi
  __shared__ __align__(16) u16 Xl[49 * PST];  // [n][c] bf16 lo (x - hi)
  __shared__ __align__(16) u16 Ph[50 * PST];  // [p][c] bf16 hi
  __shared__ __align__(16) u16 Pl[50 * PST];  // [p][c] bf16 lo
  __shared__ float Ss[49 * SST];              // [n][p] f32 scores
  const int b = blockIdx.x;
  const int t = threadIdx.x;
  const float* xb = x + (size_t)b * 12544;

  // phase 1: load x (c-major), split hi/lo, store transposed [n][c]
  for (int j = t; j < 12544; j += 1024) {
    int c = j / 49, n = j - c * 49;
    float v = xb[j];
    u16 hi = f2bf(v);
    u16 lo = f2bf(v - bf2f(hi));
    Xh[n * PST + c] = hi;
    Xl[n * PST + c] = lo;
  }
  __syncthreads();

  // phase 2: adaptive-avg pools -> Ph/Pl (LDS) + POOL (global bf16)
  for (int j = t; j < 12800; j += 1024) {
    int p = j >> 8, c = j & 255;
    int k, pl, r0, nr, c0, nc;
    pool_geom(p, k, pl, r0, nr, c0, nc);
    float s = 0.f;
    for (int r = 0; r < nr; ++r)
      for (int q = 0; q < nc; ++q) {
        int idx = ((r0 + r) * 7 + c0 + q) * PST + c;
        s += bf2f(Xh[idx]) + bf2f(Xl[idx]);
      }
    s *= (1.0f / (float)(nr * nc));
    u16 hi = f2bf(s);
    u16 lo = f2bf(s - bf2f(hi));
    Ph[p * PST + c] = hi;
    Pl[p * PST + c] = lo;
    POOL[((size_t)(seg_gb(k) + b * seg_pc(k) + pl)) * 256 + c] = hi;  // hi == f2bf(s)
  }
  __syncthreads();

  // phase 3: scores S[n][p] = X @ P^T via MFMA, hi/lo split (drop lo*lo)
  {
    const int wv = t >> 6, l = t & 63;
    const int lr = l & 15, lg = l >> 4;
    const int mi = wv & 3, pi = wv >> 2;       // 4x4 tiles of 16x16 over [64n][64p]
    int an = mi * 16 + lr; if (an > 48) an = 48;   // clamp -> broadcast
    int bp = pi * 16 + lr; if (bp > 49) bp = 49;
    f4v acc = {};
    #pragma unroll
    for (int kk = 0; kk < 8; ++kk) {
      int ko = kk * 32 + lg * 8;
      short8 ah = *(const short8*)(Xh + an * PST + ko);
      short8 al = *(const short8*)(Xl + an * PST + ko);
      short8 bh = *(const short8*)(Ph + bp * PST + ko);
      short8 bl = *(const short8*)(Pl + bp * PST + ko);
      acc = __builtin_amdgcn_mfma_f32_16x16x32_bf16(
          __builtin_bit_cast(bf16x8, ah), __builtin_bit_cast(bf16x8, bh), acc, 0, 0, 0);
      acc = __builtin_amdgcn_mfma_f32_16x16x32_bf16(
          __builtin_bit_cast(bf16x8, ah), __builtin_bit_cast(bf16x8, bl), acc, 0, 0, 0);
      acc = __builtin_amdgcn_mfma_f32_16x16x32_bf16(
          __builtin_bit_cast(bf16x8, al), __builtin_bit_cast(bf16x8, bh), acc, 0, 0, 0);
    }
    #pragma unroll
    for (int r = 0; r < 4; ++r) {
      int n = mi * 16 + lg * 4 + r;
      int p = pi * 16 + lr;
      if (n < 49 && p < 50) Ss[n * SST + p] = acc[r];
    }
  }
  __syncthreads();

  // phase 4: per-(n, tier) softmax -> ATTN f32
  if (t < 196) {
    int n = t >> 2, k = t & 3;
    int s0 = seg_s0(k), pc = seg_pc(k);
    float m = -3.0e38f;
    for (int i = 0; i < pc; ++i) m = fmaxf(m, Ss[n * SST + s0 + i]);
    float sum = 0.f;
    for (int i = 0; i < pc; ++i) sum += __expf(Ss[n * SST + s0 + i] - m);
    float inv = 1.0f / sum;
    float* ab = ATTN + (size_t)b * 2450 + n * 50 + s0;
    for (int i = 0; i < pc; ++i) ab[i] = __expf(Ss[n * SST + s0 + i] - m) * inv;
  }
}

// ---------------- K3' v2: per-sample MFMA scat + conv + residual ----------------
// Stage A (per tier k, per 128-col half): scatCh[64 n][128 o'] = relu(attn_k @ Y_k)
// Stage B: acc[n][c] += scatCh @ WCATB[c][k*256+h*128+o']   (K-reduced over all o)
// Epilogue: XF[n][c] = acc + xS[n][c]
// LDS = 5.1 + 25.9 + 32 + 16 = ~79 KB -> 2 blocks/CU.
__global__ __launch_bounds__(512, 4) void k_scat_conv(
    const u16* __restrict__ Y, const float* __restrict__ ATTN,
    const u16* __restrict__ WCATB, const float* __restrict__ x,
    u16* __restrict__ XF)
{
  __shared__ __align__(16) u16 attnB[49 * 52];    // [n][p] bf16, stride 52
  __shared__ __align__(16) u16 xS[49 * 264];      // [n][c] bf16, stride 264
  __shared__ __align__(16) u16 YT[256 * 64];      // [c][p] bf16, sigma-swizzled
  __shared__ __align__(16) u16 scatCh[64 * 128];  // [n][o'] bf16, swizzled
  const int b = blockIdx.x;
  const int t = threadIdx.x;
  const int wv = t >> 6, l = t & 63;
  const int lr = l & 15, lg = l >> 4;

  // prologue staging
  for (int i = t; i < 2450; i += 512) {
    int n = i / 50, p = i - n * 50;
    attnB[n * 52 + p] = f2bf(ATTN[(size_t)b * 2450 + i]);
  }
  for (int i = t; i < 12544; i += 512) {
    int c = i / 49, n = i - c * 49;
    xS[n * 264 + c] = f2bf(x[(size_t)b * 12544 + i]);
  }
  {
    int4 zz; zz.x = 0; zz.y = 0; zz.z = 0; zz.w = 0;
    int4* z = (int4*)YT;
    #pragma unroll
    for (int i = 0; i < 4; ++i) z[t + i * 512] = zz;  // zero all 64 p-rows once
  }
  __syncthreads();

  f4v acc[4][2] = {};

  for (int k = 0; k < 4; ++k) {
    const int pc = seg_pc(k), s0 = seg_s0(k), gb = seg_gb(k);
    const int kks = (k == 3) ? 2 : 1;

    // restage YT rows [0,pc): tiers ascend in pc, so rows >= pc stay zero
    for (int i = t; i < pc * 256; i += 512) {
      int p = i >> 8, c = i & 255;
      u32 sig = (u32)(((c & 7) ^ ((c >> 3) & 7)) << 4);
      u16 v = Y[((size_t)(gb + b * pc + p)) * 256 + c];
      *(u16*)((char*)YT + c * 128 + ((2u * p) ^ sig)) = v;
    }
    __syncthreads();

    for (int h = 0; h < 2; ++h) {
      // ---- stage A: scat chunk for c' in [h*128, h*128+128) ----
      {
        const int cB = h * 128 + wv * 16 + lr;
        const u32 sig = (u32)(((cB & 7) ^ ((cB >> 3) & 7)) << 4);
        f4v sacc[4] = {};
        for (int kk = 0; kk < kks; ++kk) {
          short8 bfv = *(const short8*)((const char*)YT + cB * 128 + (((u32)(kk * 64 + lg * 16)) ^ sig));
          #pragma unroll
          for (int mi = 0; mi < 4; ++mi) {
            int n = mi * 16 + lr;
            short8 af;
            #pragma unroll
            for (int j = 0; j < 8; ++j) {
              int p = kk * 32 + lg * 8 + j;
              u16 v = attnB[(n < 49 ? n : 0) * 52 + s0 + (p < pc ? p : 0)];
              af[j] = (n < 49 && p < pc) ? (short)v : (short)0;
            }
            sacc[mi] = __builtin_amdgcn_mfma_f32_16x16x32_bf16(
                __builtin_bit_cast(bf16x8, af), __builtin_bit_cast(bf16x8, bfv),
                sacc[mi], 0, 0, 0);
          }
        }
        #pragma unroll
        for (int mi = 0; mi < 4; ++mi) {
          #pragma unroll
          for (int r = 0; r < 4; ++r) {
            int n = mi * 16 + lg * 4 + r;
            int op = wv * 16 + lr;
            *(u16*)((char*)scatCh + n * 256 + ((2u * op) ^ (u32)((n & 7) << 4))) =
                f2bf(fmaxf(sacc[mi][r], 0.f));
          }
        }
      }
      __syncthreads();
      // ---- stage B: acc += scatCh @ WCATB slice ----
      {
        #pragma unroll
        for (int kk = 0; kk < 4; ++kk) {
          short8 af2[4];
          #pragma unroll
          for (int mi = 0; mi < 4; ++mi) {
            int n = mi * 16 + lr;
            af2[mi] = *(const short8*)((const char*)scatCh + n * 256 +
                        (((u32)(kk * 64 + lg * 16)) ^ (u32)((n & 7) << 4)));
          }
          #pragma unroll
          for (int ni = 0; ni < 2; ++ni) {
            int c = wv * 32 + ni * 16 + lr;
            short8 bf2 = *(const short8*)(WCATB + (size_t)c * 1024 +
                          k * 256 + h * 128 + kk * 32 + lg * 8);
            #pragma unroll
            for (int mi = 0; mi < 4; ++mi)
              acc[mi][ni] = __builtin_amdgcn_mfma_f32_16x16x32_bf16(
                  __builtin_bit_cast(bf16x8, af2[mi]), __builtin_bit_cast(bf16x8, bf2),
                  acc[mi][ni], 0, 0, 0);
          }
        }
      }
      __syncthreads();
    }
  }

  // epilogue: XF[n][c] = acc + x (from xS)
  #pragma unroll
  for (int mi = 0; mi < 4; ++mi) {
    #pragma unroll
    for (int r = 0; r < 4; ++r) {
      int n = mi * 16 + lg * 4 + r;
      if (n < 49) {
        #pragma unroll
        for (int ni = 0; ni < 2; ++ni) {
          int c = wv * 32 + ni * 16 + lr;
          union { u32 u; float f; } xv; xv.u = (u32)xS[n * 264 + c] << 16;
          XF[((size_t)b * 49 + n) * 256 + c] = f2bf(acc[mi][ni][r] + xv.f);
        }
      }
    }
  }
}

// ---------------- 128x128 bf16 MFMA GEMM, m97-structure ----------------
template<bool OBF16>
__global__ __launch_bounds__(256) void gemm_k(
    const u16* __restrict__ A, int lda,
    const u16* __restrict__ W, int ldb,
    void* __restrict__ Cout, int ldc,
    int mtiles, int ntiles, int scW, int kchunk,
    const float* __restrict__ bias, int relu)
{
  __shared__ char lds[32768];
  char* ldsA = lds;
  char* ldsB = lds + 16384;
  const int tid = threadIdx.x;
  const int wv = tid >> 6, l = tid & 63;

  // bijective XCD swizzle (m204): same-XCD blocks -> contiguous wg
  const int nwg = gridDim.x;
  const int q = nwg >> 3, r8 = nwg & 7;
  const int xcd = blockIdx.x & 7, pos = blockIdx.x >> 3;
  int wg = (xcd < r8 ? xcd * (q + 1) : r8 * (q + 1) + (xcd - r8) * q) + pos;

  const int sub = mtiles * ntiles;
  const int ks = wg / sub; wg -= ks * sub;
  const int band = mtiles * scW;
  const int sc = wg / band; wg -= sc * band;
  const int mt = wg / scW;
  const int nt = sc * scW + (wg - mt * scW);
  const int m0 = mt * 128, n0 = nt * 128;
  const int k0 = ks * kchunk;

  const char* Ab = (const char*)(A + (size_t)m0 * lda + k0);
  const char* Bb = (const char*)(W + (size_t)n0 * ldb + k0);
  const int ldab = lda * 2, ldbb = ldb * 2;
  const int rloc = l >> 3;                    // row within 8-row group
  const int swz = ((l & 7) ^ rloc) << 4;      // pre-swizzled byte-in-row (involution)

  auto stage = [&](int kt) {
    const char* Ak = Ab + kt * 2 + swz;
    const char* Bk = Bb + kt * 2 + swz;
    #pragma unroll
    for (int it = 0; it < 4; ++it) {
      int rb = (it * 4 + wv) * 8;
      gl16(Ak + (size_t)(rb + rloc) * ldab, ldsA + rb * 128);
      gl16(Bk + (size_t)(rb + rloc) * ldbb, ldsB + rb * 128);
    }
  };

  const int wr = (wv >> 1) * 64, wc = (wv & 1) * 64;
  const int lr = l & 15, lg = l >> 4;
  f4v acc[4][4] = {};

  stage(0);
  for (int kt = 0; kt < kchunk; kt += 64) {
    __syncthreads();  // drains vmcnt: tile ready
    #pragma unroll
    for (int kk = 0; kk < 2; ++kk) {
      short8 af[4], bfv[4];
      #pragma unroll
      for (int mi = 0; mi < 4; ++mi) {
        int rA = wr + mi * 16 + lr;
        af[mi] = *(const short8*)(ldsA + rA * 128 + ((kk * 64 + lg * 16) ^ ((rA & 7) << 4)));
      }
      #pragma unroll
      for (int ni = 0; ni < 4; ++ni) {
        int rB = wc + ni * 16 + lr;
        bfv[ni] = *(const short8*)(ldsB + rB * 128 + ((kk * 64 + lg * 16) ^ ((rB & 7) << 4)));
      }
      #pragma unroll
      for (int mi = 0; mi < 4; ++mi)
        #pragma unroll
        for (int ni = 0; ni < 4; ++ni)
          acc[mi][ni] = __builtin_amdgcn_mfma_f32_16x16x32_bf16(
              __builtin_bit_cast(bf16x8, af[mi]),
              __builtin_bit_cast(bf16x8, bfv[ni]),
              acc[mi][ni], 0, 0, 0);
    }
    if (kt + 64 < kchunk) { __syncthreads(); stage(kt + 64); }
  }

  const size_t crow0 = (size_t)ks * mtiles * 128 + m0;
  #pragma unroll
  for (int ni = 0; ni < 4; ++ni) {
    int gc = n0 + wc + ni * 16 + lr;
    float bv = bias ? bias[gc] : 0.f;
    #pragma unroll
    for (int mi = 0; mi < 4; ++mi) {
      #pragma unroll
      for (int j = 0; j < 4; ++j) {
        size_t gr = crow0 + wr + mi * 16 + lg * 4 + j;
        float v = acc[mi][ni][j] + bv;
        if (relu) v = fmaxf(v, 0.f);
        if (OBF16) ((u16*)Cout)[gr * ldc + gc] = f2bf(v);
        else       ((float*)Cout)[gr * ldc + gc] = v;
      }
    }
  }
}

// ---------------- reduce split-K partials + bias + relu -> bf16 ----------------
__global__ __launch_bounds__(256) void k_red6(
    const float* __restrict__ P, const float* __restrict__ bias, u16* __restrict__ XC1)
{
  const size_t base = ((size_t)blockIdx.x * 256 + threadIdx.x) * 8;  // 8.4M elems
  f4v a0 = *(const f4v*)(P + base);
  f4v a1 = *(const f4v*)(P + base + 4);
  const float* P2 = P + 8388608;
  f4v b0 = *(const f4v*)(P2 + base);
  f4v b1 = *(const f4v*)(P2 + base + 4);
  int col = (int)(base & 2047u);
  u16 o[8];
  #pragma unroll
  for (int j = 0; j < 4; ++j) o[j]     = f2bf(fmaxf(a0[j] + b0[j] + bias[col + j], 0.f));
  #pragma unroll
  for (int j = 0; j < 4; ++j) o[4 + j] = f2bf(fmaxf(a1[j] + b1[j] + bias[col + 4 + j], 0.f));
  *(int4*)(XC1 + base) = *(const int4*)(&o[0]);
}

extern "C" void kernel_launch(void* const* d_in, const int* in_sizes, int n_in,
                              void* d_out, int out_size, void* d_ws, size_t ws_size,
                              hipStream_t stream)
{
  (void)in_sizes; (void)n_in; (void)out_size; (void)ws_size;
  const float* x    = (const float*)d_in[0];
  const float* w1   = (const float*)d_in[1];
  const float* w2   = (const float*)d_in[2];
  const float* w3   = (const float*)d_in[3];
  const float* w6   = (const float*)d_in[4];
  const float* wcat = (const float*)d_in[5];
  const float* f6cw = (const float*)d_in[6];
  const float* f6cb = (const float*)d_in[7];
  const float* f7cw = (const float*)d_in[8];
  const float* f7cb = (const float*)d_in[9];
  const float* f6rw = (const float*)d_in[10];
  const float* f6rb = (const float*)d_in[11];
  const float* f7rw = (const float*)d_in[12];
  const float* f7rb = (const float*)d_in[13];

  char* ws = (char*)d_ws;
  u16*   W14B  = (u16*)(ws);
  u16*   WCATB = (u16*)(ws + 524288);
  u16*   W6P   = (u16*)(ws + 1048576);
  u16*   W7B   = (u16*)(ws + 52428800);
  float* BIAS6 = (float*)(ws + 56623104);
  u16*   POOL  = (u16*)(ws + 56631296);
  u16*   XF    = POOL;                      // overlay: POOL dead after convs
  float* ATTN  = (float*)(ws + 161488896);
  u16*   XC1   = (u16*)(ws + 161488896);    // overlay: ATTN dead after scat
  u16*   Y     = (u16*)(ws + 201629696);
  float* PART  = (float*)(ws + 201629696);  // overlay: Y dead after scat (2x4096x2048 f32)

  k_pack<<<dim3(2048), dim3(256), 0, stream>>>(w1, w2, w3, w6, wcat, f6cw, f6rw,
                                               f7cw, f7rw, f6cb, f6rb,
                                               W14B, WCATB, W6P, W7B, BIAS6);
  k_pool_attn<<<dim3(4096), dim3(1024), 0, stream>>>(x, POOL, ATTN);

  for (int k = 0; k < 4; ++k) {
    int gb = (k == 0) ? 0 : (k == 1) ? 4096 : (k == 2) ? 20480 : 57344;
    int pc = (k == 0) ? 1 : (k == 1) ? 4 : (k == 2) ? 9 : 36;
    int mtl = 32 * pc;
    gemm_k<true><<<dim3(mtl * 2), dim3(256), 0, stream>>>(
        POOL + (size_t)gb * 256, 256, W14B + k * 65536, 256,
        (void*)(Y + (size_t)gb * 256), 256, mtl, 2, 2, 256, nullptr, 0);
  }

  k_scat_conv<<<dim3(4096), dim3(512), 0, stream>>>(Y, ATTN, WCATB, x, XF);

  // fc6 (fused c|r): M=4096, N=2048, K=12544, split-K=2 -> f32 partials
  gemm_k<false><<<dim3(1024), dim3(256), 0, stream>>>(
      XF, 12544, W6P, 12544, (void*)PART, 2048, 32, 16, 8, 6272, nullptr, 0);
  k_red6<<<dim3(4096), dim3(256), 0, stream>>>(PART, BIAS6, XC1);

  float* out = (float*)d_out;
  gemm_k<false><<<dim3(256), dim3(256), 0, stream>>>(
      XC1, 2048, W7B, 1024, (void*)out, 1024, 32, 8, 8, 1024, f7cb, 0);
  gemm_k<false><<<dim3(256), dim3(256), 0, stream>>>(
      XC1 + 1024, 2048, W7B + 1048576, 1024,
      (void*)(out + (size_t)4096 * 1024), 1024, 32, 8, 8, 1024, f7rb, 1);
}

// Round 8
// 1660.848 us; speedup vs baseline: 1.8644x; 1.0692x over previous
//
#include <hip/hip_runtime.h>

typedef unsigned short u16;
typedef unsigned int   u32;
typedef float  f4v     __attribute__((ext_vector_type(4)));
typedef short  short4v __attribute__((ext_vector_type(4)));
typedef short  short8  __attribute__((ext_vector_type(8)));
typedef __bf16 bf16x8  __attribute__((ext_vector_type(8)));

// ws layout (bytes):
//   W14B   @ 0          524288   (w1,w2,w3,w6 bf16)
//   WCATB  @ 524288     524288
//   W6P    @ 1048576    51380224 ([2048][12544] bf16, permuted k'=n*256+c)
//   W7B    @ 52428800   4194304  ([2][1024][1024] bf16)
//   BIAS6  @ 56623104   8192     ([2048] f32)
//   POOL   @ 56631296   104857600  ([204800][256] bf16)  -- XF overlays after convs
//   ATTN   @ 161488896  40140800   ([4096][2450] f32)    -- XC1 overlays after scat
//   Y      @ 201629696  104857600  ([204800][256] bf16)  -- PART (67MB f32) overlays after scat
// total = 306487296 bytes

__device__ __forceinline__ u16 f2bf(float f) {
  union { float f; u32 u; } v; v.f = f;
  return (u16)((v.u + 0x7FFFu + ((v.u >> 16) & 1u)) >> 16);
}
__device__ __forceinline__ float bf2f(u16 h) {
  union { u32 u; float f; } v; v.u = (u32)h << 16;
  return v.f;
}

__device__ __forceinline__ int seg_gb(int k) { return (k == 0) ? 0 : (k == 1) ? 4096 : (k == 2) ? 20480 : 57344; }
__device__ __forceinline__ int seg_pc(int k) { return (k == 0) ? 1 : (k == 1) ? 4 : (k == 2) ? 9 : 36; }
__device__ __forceinline__ int seg_s0(int k) { return (k == 0) ? 0 : (k == 1) ? 1 : (k == 2) ? 5 : 14; }

// async global->LDS, 16B per lane; LDS dest = wave-uniform base + lane*16
__device__ __forceinline__ void gl16(const void* g, void* l) {
  __builtin_amdgcn_global_load_lds(
      (const __attribute__((address_space(1))) unsigned int*)g,
      (__attribute__((address_space(3))) unsigned int*)l, 16, 0, 0);
}

// ---------------- K0: pack / convert / permute weights ----------------
__global__ __launch_bounds__(256) void k_pack(
    const float* __restrict__ w1, const float* __restrict__ w2,
    const float* __restrict__ w3, const float* __restrict__ w6,
    const float* __restrict__ wcat,
    const float* __restrict__ f6c, const float* __restrict__ f6r,
    const float* __restrict__ f7c, const float* __restrict__ f7r,
    const float* __restrict__ b6c, const float* __restrict__ b6r,
    u16* __restrict__ W14B, u16* __restrict__ WCATB, u16* __restrict__ W6P,
    u16* __restrict__ W7B, float* __restrict__ BIAS6)
{
  const u32 total = 28313600u;
  for (u32 t = blockIdx.x * 256u + threadIdx.x; t < total; t += gridDim.x * 256u) {
    if (t < 262144u) {
      u32 a = t >> 16, i = t & 65535u;
      const float* s = (a == 0) ? w1 : (a == 1) ? w2 : (a == 2) ? w3 : w6;
      W14B[t] = f2bf(s[i]);
    } else if (t < 524288u) {
      u32 i = t - 262144u;
      WCATB[i] = f2bf(wcat[i]);
    } else if (t < 26214400u) {
      u32 j = t - 524288u;
      u32 r = j / 12544u, rem = j - r * 12544u;
      u32 n = rem >> 8, c = rem & 255u;  // out index = n*256 + c
      const float* s = (r < 1024u) ? f6c : f6r;
      W6P[j] = f2bf(s[(size_t)(r & 1023u) * 12544u + c * 49u + n]);
    } else if (t < 28311552u) {
      u32 j = t - 26214400u;
      W7B[j] = f2bf((j < 1048576u) ? f7c[j] : f7r[j - 1048576u]);
    } else {
      u32 j = t - 28311552u;
      BIAS6[j] = (j < 1024u) ? b6c[j] : b6r[j - 1024u];
    }
  }
}

// ---------------- K1 v2: pooled + MFMA scores (hi/lo bf16) + softmax ----------------
#define PST 272   // u16 row stride: 544B = 136 words == 8 mod 32 -> even bank spread
#define SST 52

__device__ __forceinline__ void pool_geom(int p, int& k, int& pl, int& r0, int& nr, int& c0, int& nc) {
  if (p == 0)      { k = 0; pl = 0;      r0 = 0; nr = 7; c0 = 0; nc = 7; }
  else if (p < 5)  { k = 1; pl = p - 1;  int i = pl >> 1, j = pl & 1; r0 = i * 3; nr = 4; c0 = j * 3; nc = 4; }
  else if (p < 14) { k = 2; pl = p - 5;  int i = pl / 3,  j = pl % 3; r0 = i * 2; nr = 3; c0 = j * 2; nc = 3; }
  else             { k = 3; pl = p - 14; int i = pl / 6,  j = pl % 6; r0 = i;     nr = 2; c0 = j;     nc = 2; }
}

__global__ __launch_bounds__(1024) void k_pool_attn(
    const float* __restrict__ x, u16* __restrict__ POOL, float* __restrict__ ATTN)
{
  __shared__ __align__(16) u16 Xh[49 * PST];  // [n][c] bf16 hi
  __shared__ __align__(16) u16 Xl[49 * PST];  // [n][c] bf16 lo (x - hi)
  __shared__ __align__(16) u16 Ph[50 * PST];  // [p][c] bf16 hi
  __shared__ __align__(16) u16 Pl[50 * PST];  // [p][c] bf16 lo
  __shared__ float Ss[49 * SST];              // [n][p] f32 scores
  const int b = blockIdx.x;
  const int t = threadIdx.x;
  const float* xb = x + (size_t)b * 12544;

  // phase 1: load x (c-major), split hi/lo, store transposed [n][c]
  for (int j = t; j < 12544; j += 1024) {
    int c = j / 49, n = j - c * 49;
    float v = xb[j];
    u16 hi = f2bf(v);
    u16 lo = f2bf(v - bf2f(hi));
    Xh[n * PST + c] = hi;
    Xl[n * PST + c] = lo;
  }
  __syncthreads();

  // phase 2: adaptive-avg pools -> Ph/Pl (LDS) + POOL (global bf16)
  for (int j = t; j < 12800; j += 1024) {
    int p = j >> 8, c = j & 255;
    int k, pl, r0, nr, c0, nc;
    pool_geom(p, k, pl, r0, nr, c0, nc);
    float s = 0.f;
    for (int r = 0; r < nr; ++r)
      for (int q = 0; q < nc; ++q) {
        int idx = ((r0 + r) * 7 + c0 + q) * PST + c;
        s += bf2f(Xh[idx]) + bf2f(Xl[idx]);
      }
    s *= (1.0f / (float)(nr * nc));
    u16 hi = f2bf(s);
    u16 lo = f2bf(s - bf2f(hi));
    Ph[p * PST + c] = hi;
    Pl[p * PST + c] = lo;
    POOL[((size_t)(seg_gb(k) + b * seg_pc(k) + pl)) * 256 + c] = hi;  // hi == f2bf(s)
  }
  __syncthreads();

  // phase 3: scores S[n][p] = X @ P^T via MFMA, hi/lo split (drop lo*lo)
  {
    const int wv = t >> 6, l = t & 63;
    const int lr = l & 15, lg = l >> 4;
    const int mi = wv & 3, pi = wv >> 2;       // 4x4 tiles of 16x16 over [64n][64p]
    int an = mi * 16 + lr; if (an > 48) an = 48;   // clamp -> broadcast
    int bp = pi * 16 + lr; if (bp > 49) bp = 49;
    f4v acc = {};
    #pragma unroll
    for (int kk = 0; kk < 8; ++kk) {
      int ko = kk * 32 + lg * 8;
      short8 ah = *(const short8*)(Xh + an * PST + ko);
      short8 al = *(const short8*)(Xl + an * PST + ko);
      short8 bh = *(const short8*)(Ph + bp * PST + ko);
      short8 bl = *(const short8*)(Pl + bp * PST + ko);
      acc = __builtin_amdgcn_mfma_f32_16x16x32_bf16(
          __builtin_bit_cast(bf16x8, ah), __builtin_bit_cast(bf16x8, bh), acc, 0, 0, 0);
      acc = __builtin_amdgcn_mfma_f32_16x16x32_bf16(
          __builtin_bit_cast(bf16x8, ah), __builtin_bit_cast(bf16x8, bl), acc, 0, 0, 0);
      acc = __builtin_amdgcn_mfma_f32_16x16x32_bf16(
          __builtin_bit_cast(bf16x8, al), __builtin_bit_cast(bf16x8, bh), acc, 0, 0, 0);
    }
    #pragma unroll
    for (int r = 0; r < 4; ++r) {
      int n = mi * 16 + lg * 4 + r;
      int p = pi * 16 + lr;
      if (n < 49 && p < 50) Ss[n * SST + p] = acc[r];
    }
  }
  __syncthreads();

  // phase 4: per-(n, tier) softmax -> ATTN f32
  if (t < 196) {
    int n = t >> 2, k = t & 3;
    int s0 = seg_s0(k), pc = seg_pc(k);
    float m = -3.0e38f;
    for (int i = 0; i < pc; ++i) m = fmaxf(m, Ss[n * SST + s0 + i]);
    float sum = 0.f;
    for (int i = 0; i < pc; ++i) sum += __expf(Ss[n * SST + s0 + i] - m);
    float inv = 1.0f / sum;
    float* ab = ATTN + (size_t)b * 2450 + n * 50 + s0;
    for (int i = 0; i < pc; ++i) ab[i] = __expf(Ss[n * SST + s0 + i] - m) * inv;
  }
}

// ---------------- K3' v3: operand-swapped stage A, vectorized LDS, coalesced XF ----------------
// Stage A (tier k, half h): mfma(A=Y^T, B=attn) -> scat chunk C[op][n]; lane holds
//   4 consecutive op at fixed n -> ds_write_b64 into scatCh[n][op] (swz (n&7)<<4).
// Stage B: acc[n][c] += scatCh @ WCATB slice (unchanged from v2).
// Epilogue: stage x -> LDS, add residual in LDS, coalesced int4 XF write.
// LDS: YT [256][72 u16] @0 (36864B) | attnT [64][160 u16] @36864 (20480B) |
//      scatCh [64][128 u16 swz] @57344 (16384B)  -> total 73728B (2 blocks/CU).
// Epilogue union: xres[49*264 u16] @0 | res[49*264 u16] @26624.
__global__ __launch_bounds__(512, 4) void k_scat_conv(
    const u16* __restrict__ Y, const float* __restrict__ ATTN,
    const u16* __restrict__ WCATB, const float* __restrict__ x,
    u16* __restrict__ XF)
{
  __shared__ __align__(16) char U[73728];
  const int b = blockIdx.x;
  const int t = threadIdx.x;
  const int wv = t >> 6, l = t & 63;
  const int lr = l & 15, lg = l >> 4;

  u16* YT = (u16*)U;                    // [c][72], stride 144B (== 4 banks mod 32)
  u16* AT = (u16*)(U + 36864);          // [n][160], tier regions at u16 off {0,32,64,96}
  char* SC = U + 57344;                 // scatCh [n][128], row 256B, swz ((n&7)<<4)

  // zero YT + attnT (57344 B): pads/tails must be 0 (no masks in MFMA path)
  {
    int4 zz; zz.x = 0; zz.y = 0; zz.z = 0; zz.w = 0;
    int4* z = (int4*)U;
    for (int i = t; i < 3584; i += 512) z[i] = zz;
  }
  __syncthreads();

  // stage attn -> attnT per-tier regions (zeros elsewhere)
  for (int i = t; i < 2450; i += 512) {
    int n = i / 50, pg = i - n * 50;
    int k = (pg < 1) ? 0 : (pg < 5) ? 1 : (pg < 14) ? 2 : 3;
    int pl = pg - seg_s0(k);
    AT[n * 160 + k * 32 + pl] = f2bf(ATTN[(size_t)b * 2450 + i]);
  }

  f4v acc[4][2] = {};

  for (int k = 0; k < 4; ++k) {
    const int pc = seg_pc(k), gb = seg_gb(k);
    const int kks = (k == 3) ? 2 : 1;

    // restage YT[c][p], p<pc (rows >= pc stay zero: tiers ascend in pc)
    for (int i = t; i < pc * 256; i += 512) {
      int p = i >> 8, c = i & 255;
      YT[c * 72 + p] = Y[((size_t)(gb + b * pc + p)) * 256 + c];
    }
    __syncthreads();

    for (int h = 0; h < 2; ++h) {
      // ---- stage A: C[op][n] = sum_p Y^T[op][p] * attn[p][n] ----
      {
        const int cy = h * 128 + wv * 16 + lr;       // A row = op channel
        f4v sacc[4] = {};
        for (int kk = 0; kk < kks; ++kk) {
          short8 yf = *(const short8*)(YT + cy * 72 + kk * 32 + lg * 8);
          #pragma unroll
          for (int ni = 0; ni < 4; ++ni) {
            short8 af = *(const short8*)(AT + (ni * 16 + lr) * 160 + k * 32 + kk * 32 + lg * 8);
            sacc[ni] = __builtin_amdgcn_mfma_f32_16x16x32_bf16(
                __builtin_bit_cast(bf16x8, yf), __builtin_bit_cast(bf16x8, af),
                sacc[ni], 0, 0, 0);
          }
        }
        const u32 opb = (u32)((wv * 16 + lg * 4) * 2);   // byte offset of 4 consecutive op
        #pragma unroll
        for (int ni = 0; ni < 4; ++ni) {
          int n = ni * 16 + lr;
          short4v ov;
          #pragma unroll
          for (int r = 0; r < 4; ++r) ov[r] = (short)f2bf(fmaxf(sacc[ni][r], 0.f));
          *(short4v*)(SC + n * 256 + (opb ^ (u32)((n & 7) << 4))) = ov;
        }
      }
      __syncthreads();
      // ---- stage B: acc += scatCh @ WCATB slice ----
      {
        #pragma unroll
        for (int kk = 0; kk < 4; ++kk) {
          short8 af2[4];
          #pragma unroll
          for (int mi = 0; mi < 4; ++mi) {
            int n = mi * 16 + lr;
            af2[mi] = *(const short8*)(SC + n * 256 +
                        (((u32)(kk * 64 + lg * 16)) ^ (u32)((n & 7) << 4)));
          }
          #pragma unroll
          for (int ni = 0; ni < 2; ++ni) {
            int c = wv * 32 + ni * 16 + lr;
            short8 bf2 = *(const short8*)(WCATB + (size_t)c * 1024 +
                          k * 256 + h * 128 + kk * 32 + lg * 8);
            #pragma unroll
            for (int mi = 0; mi < 4; ++mi)
              acc[mi][ni] = __builtin_amdgcn_mfma_f32_16x16x32_bf16(
                  __builtin_bit_cast(bf16x8, af2[mi]), __builtin_bit_cast(bf16x8, bf2),
                  acc[mi][ni], 0, 0, 0);
          }
        }
      }
      __syncthreads();
    }
  }

  // epilogue: stage x -> xres, add residual in LDS, coalesced XF write
  u16* xres = (u16*)U;                  // [n][264] bf16 (overlays YT/AT, now dead)
  u16* res  = (u16*)(U + 26624);        // [n][264] bf16
  for (int i = t; i < 12544; i += 512) {
    int c = i / 49, n = i - c * 49;
    xres[n * 264 + c] = f2bf(x[(size_t)b * 12544 + i]);
  }
  __syncthreads();
  #pragma unroll
  for (int mi = 0; mi < 4; ++mi) {
    #pragma unroll
    for (int r = 0; r < 4; ++r) {
      int n = mi * 16 + lg * 4 + r;
      if (n < 49) {
        #pragma unroll
        for (int ni = 0; ni < 2; ++ni) {
          int c = wv * 32 + ni * 16 + lr;
          res[n * 264 + c] = f2bf(acc[mi][ni][r] + bf2f(xres[n * 264 + c]));
        }
      }
    }
  }
  __syncthreads();
  for (int j = t; j < 1568; j += 512) {   // 49 rows x 32 int4 = full 512B lines
    int n = j >> 5, w = j & 31;
    *(int4*)(XF + ((size_t)b * 49 + n) * 256 + w * 8) = *(const int4*)(res + n * 264 + w * 8);
  }
}

// ---------------- 128x128 bf16 MFMA GEMM, m97-structure ----------------
template<bool OBF16>
__global__ __launch_bounds__(256) void gemm_k(
    const u16* __restrict__ A, int lda,
    const u16* __restrict__ W, int ldb,
    void* __restrict__ Cout, int ldc,
    int mtiles, int ntiles, int scW, int kchunk,
    const float* __restrict__ bias, int relu)
{
  __shared__ char lds[32768];
  char* ldsA = lds;
  char* ldsB = lds + 16384;
  const int tid = threadIdx.x;
  const int wv = tid >> 6, l = tid & 63;

  // bijective XCD swizzle (m204): same-XCD blocks -> contiguous wg
  const int nwg = gridDim.x;
  const int q = nwg >> 3, r8 = nwg & 7;
  const int xcd = blockIdx.x & 7, pos = blockIdx.x >> 3;
  int wg = (xcd < r8 ? xcd * (q + 1) : r8 * (q + 1) + (xcd - r8) * q) + pos;

  const int sub = mtiles * ntiles;
  const int ks = wg / sub; wg -= ks * sub;
  const int band = mtiles * scW;
  const int sc = wg / band; wg -= sc * band;
  const int mt = wg / scW;
  const int nt = sc * scW + (wg - mt * scW);
  const int m0 = mt * 128, n0 = nt * 128;
  const int k0 = ks * kchunk;

  const char* Ab = (const char*)(A + (size_t)m0 * lda + k0);
  const char* Bb = (const char*)(W + (size_t)n0 * ldb + k0);
  const int ldab = lda * 2, ldbb = ldb * 2;
  const int rloc = l >> 3;                    // row within 8-row group
  const int swz = ((l & 7) ^ rloc) << 4;      // pre-swizzled byte-in-row (involution)

  auto stage = [&](int kt) {
    const char* Ak = Ab + kt * 2 + swz;
    const char* Bk = Bb + kt * 2 + swz;
    #pragma unroll
    for (int it = 0; it < 4; ++it) {
      int rb = (it * 4 + wv) * 8;
      gl16(Ak + (size_t)(rb + rloc) * ldab, ldsA + rb * 128);
      gl16(Bk + (size_t)(rb + rloc) * ldbb, ldsB + rb * 128);
    }
  };

  const int wr = (wv >> 1) * 64, wc = (wv & 1) * 64;
  const int lr = l & 15, lg = l >> 4;
  f4v acc[4][4] = {};

  stage(0);
  for (int kt = 0; kt < kchunk; kt += 64) {
    __syncthreads();  // drains vmcnt: tile ready
    #pragma unroll
    for (int kk = 0; kk < 2; ++kk) {
      short8 af[4], bfv[4];
      #pragma unroll
      for (int mi = 0; mi < 4; ++mi) {
        int rA = wr + mi * 16 + lr;
        af[mi] = *(const short8*)(ldsA + rA * 128 + ((kk * 64 + lg * 16) ^ ((rA & 7) << 4)));
      }
      #pragma unroll
      for (int ni = 0; ni < 4; ++ni) {
        int rB = wc + ni * 16 + lr;
        bfv[ni] = *(const short8*)(ldsB + rB * 128 + ((kk * 64 + lg * 16) ^ ((rB & 7) << 4)));
      }
      #pragma unroll
      for (int mi = 0; mi < 4; ++mi)
        #pragma unroll
        for (int ni = 0; ni < 4; ++ni)
          acc[mi][ni] = __builtin_amdgcn_mfma_f32_16x16x32_bf16(
              __builtin_bit_cast(bf16x8, af[mi]),
              __builtin_bit_cast(bf16x8, bfv[ni]),
              acc[mi][ni], 0, 0, 0);
    }
    if (kt + 64 < kchunk) { __syncthreads(); stage(kt + 64); }
  }

  const size_t crow0 = (size_t)ks * mtiles * 128 + m0;
  #pragma unroll
  for (int ni = 0; ni < 4; ++ni) {
    int gc = n0 + wc + ni * 16 + lr;
    float bv = bias ? bias[gc] : 0.f;
    #pragma unroll
    for (int mi = 0; mi < 4; ++mi) {
      #pragma unroll
      for (int j = 0; j < 4; ++j) {
        size_t gr = crow0 + wr + mi * 16 + lg * 4 + j;
        float v = acc[mi][ni][j] + bv;
        if (relu) v = fmaxf(v, 0.f);
        if (OBF16) ((u16*)Cout)[gr * ldc + gc] = f2bf(v);
        else       ((float*)Cout)[gr * ldc + gc] = v;
      }
    }
  }
}

// ---------------- reduce split-K partials + bias + relu -> bf16 ----------------
__global__ __launch_bounds__(256) void k_red6(
    const float* __restrict__ P, const float* __restrict__ bias, u16* __restrict__ XC1)
{
  const size_t base = ((size_t)blockIdx.x * 256 + threadIdx.x) * 8;  // 8.4M elems
  f4v a0 = *(const f4v*)(P + base);
  f4v a1 = *(const f4v*)(P + base + 4);
  const float* P2 = P + 8388608;
  f4v b0 = *(const f4v*)(P2 + base);
  f4v b1 = *(const f4v*)(P2 + base + 4);
  int col = (int)(base & 2047u);
  u16 o[8];
  #pragma unroll
  for (int j = 0; j < 4; ++j) o[j]     = f2bf(fmaxf(a0[j] + b0[j] + bias[col + j], 0.f));
  #pragma unroll
  for (int j = 0; j < 4; ++j) o[4 + j] = f2bf(fmaxf(a1[j] + b1[j] + bias[col + 4 + j], 0.f));
  *(int4*)(XC1 + base) = *(const int4*)(&o[0]);
}

extern "C" void kernel_launch(void* const* d_in, const int* in_sizes, int n_in,
                              void* d_out, int out_size, void* d_ws, size_t ws_size,
                              hipStream_t stream)
{
  (void)in_sizes; (void)n_in; (void)out_size; (void)ws_size;
  const float* x    = (const float*)d_in[0];
  const float* w1   = (const float*)d_in[1];
  const float* w2   = (const float*)d_in[2];
  const float* w3   = (const float*)d_in[3];
  const float* w6   = (const float*)d_in[4];
  const float* wcat = (const float*)d_in[5];
  const float* f6cw = (const float*)d_in[6];
  const float* f6cb = (const float*)d_in[7];
  const float* f7cw = (const float*)d_in[8];
  const float* f7cb = (const float*)d_in[9];
  const float* f6rw = (const float*)d_in[10];
  const float* f6rb = (const float*)d_in[11];
  const float* f7rw = (const float*)d_in[12];
  const float* f7rb = (const float*)d_in[13];

  char* ws = (char*)d_ws;
  u16*   W14B  = (u16*)(ws);
  u16*   WCATB = (u16*)(ws + 524288);
  u16*   W6P   = (u16*)(ws + 1048576);
  u16*   W7B   = (u16*)(ws + 52428800);
  float* BIAS6 = (float*)(ws + 56623104);
  u16*   POOL  = (u16*)(ws + 56631296);
  u16*   XF    = POOL;                      // overlay: POOL dead after convs
  float* ATTN  = (float*)(ws + 161488896);
  u16*   XC1   = (u16*)(ws + 161488896);    // overlay: ATTN dead after scat
  u16*   Y     = (u16*)(ws + 201629696);
  float* PART  = (float*)(ws + 201629696);  // overlay: Y dead after scat (2x4096x2048 f32)

  k_pack<<<dim3(2048), dim3(256), 0, stream>>>(w1, w2, w3, w6, wcat, f6cw, f6rw,
                                               f7cw, f7rw, f6cb, f6rb,
                                               W14B, WCATB, W6P, W7B, BIAS6);
  k_pool_attn<<<dim3(4096), dim3(1024), 0, stream>>>(x, POOL, ATTN);

  for (int k = 0; k < 4; ++k) {
    int gb = (k == 0) ? 0 : (k == 1) ? 4096 : (k == 2) ? 20480 : 57344;
    int pc = (k == 0) ? 1 : (k == 1) ? 4 : (k == 2) ? 9 : 36;
    int mtl = 32 * pc;
    gemm_k<true><<<dim3(mtl * 2), dim3(256), 0, stream>>>(
        POOL + (size_t)gb * 256, 256, W14B + k * 65536, 256,
        (void*)(Y + (size_t)gb * 256), 256, mtl, 2, 2, 256, nullptr, 0);
  }

  k_scat_conv<<<dim3(4096), dim3(512), 0, stream>>>(Y, ATTN, WCATB, x, XF);

  // fc6 (fused c|r): M=4096, N=2048, K=12544, split-K=2 -> f32 partials
  gemm_k<false><<<dim3(1024), dim3(256), 0, stream>>>(
      XF, 12544, W6P, 12544, (void*)PART, 2048, 32, 16, 8, 6272, nullptr, 0);
  k_red6<<<dim3(4096), dim3(256), 0, stream>>>(PART, BIAS6, XC1);

  float* out = (float*)d_out;
  gemm_k<false><<<dim3(256), dim3(256), 0, stream>>>(
      XC1, 2048, W7B, 1024, (void*)out, 1024, 32, 8, 8, 1024, f7cb, 0);
  gemm_k<false><<<dim3(256), dim3(256), 0, stream>>>(
      XC1 + 1024, 2048, W7B + 1048576, 1024,
      (void*)(out + (size_t)4096 * 1024), 1024, 32, 8, 8, 1024, f7rb, 1);
}